// Round 13
// baseline (438.349 us; speedup 1.0000x reference)
//
#include <hip/hip_runtime.h>
#include <hip/hip_fp16.h>

#define NN 100000
#define NE 3200000
#define FN 7
#define FE 6
#define FG 64
#define HID 32
#define EPB 4096                          // edges per P1 block
#define NBLK1 ((NE + EPB - 1) / EPB)      // 782
#define NBKT ((NN + 255) >> 8)            // 391 coarse buckets (256 nodes each)
#define BCAP 9000                         // per-bucket capacity (mean 8192 + 8.9 sigma)
#define NB ((NN + 1023) / 1024)           // fallback scan blocks

typedef _Float16 half2_t __attribute__((ext_vector_type(2)));

__device__ __forceinline__ float leaky(float v) { return v >= 0.f ? v : 0.01f * v; }

#if defined(__has_builtin) && __has_builtin(__builtin_amdgcn_fdot2)
__device__ __forceinline__ float fdot2(half2_t a, half2_t b, float c) {
    return __builtin_amdgcn_fdot2(a, b, c, false);
}
#else
__device__ __forceinline__ float fdot2(half2_t a, half2_t b, float c) {
    return fmaf((float)a.x, (float)b.x, fmaf((float)a.y, (float)b.y, c));
}
#endif

// ======================= weight prep (runs once per launch) ===============
__global__ __launch_bounds__(256) void wprep_kernel(
    const float* __restrict__ W1, const float* __restrict__ W2,
    half2_t* __restrict__ w1t, half2_t* __restrict__ w2t)
{
    int t = threadIdx.x;
    for (int i = t; i < 32 * 7; i += 256) {
        int j = i / 7, kp = i % 7;
        int k0 = 2 * kp, k1 = 2 * kp + 1;
        half2_t v;
        v.x = (_Float16)W1[k0 * HID + j];
        v.y = (k1 < FN + FE) ? (_Float16)W1[k1 * HID + j] : (_Float16)0.f;
        w1t[i] = v;
    }
    for (int i = t; i < 32 * 16; i += 256) {
        int j = i >> 4, kp = i & 15;
        half2_t v;
        v.x = (_Float16)W2[(2 * kp) * HID + j];
        v.y = (_Float16)W2[(2 * kp + 1) * HID + j];
        w2t[i] = v;
    }
}

// ======================= primary path =====================================

// P1: coarse partition (unchanged, known-good)
__global__ __launch_bounds__(256) void p1_partition_kernel(
    const int* __restrict__ ei, int* __restrict__ gnext, int* __restrict__ pairs)
{
    __shared__ int hist[NBKT];
    __shared__ int scp[512];
    __shared__ int runbase[NBKT];
    __shared__ int stage[EPB];

    int t = threadIdx.x;
    int e0 = blockIdx.x * EPB;
    int nvalid = NE - e0; if (nvalid > EPB) nvalid = EPB;

    for (int i = t; i < NBKT; i += 256) hist[i] = 0;
    __syncthreads();

    int myc[EPB / 256];
    int myr[EPB / 256];
    #pragma unroll
    for (int i = 0; i < EPB / 256; ++i) {
        int e = e0 + i * 256 + t;
        myc[i] = -1;
        if (e < NE) {
            int col = ei[NE + e];
            myc[i] = col;
            myr[i] = atomicAdd(&hist[col >> 8], 1);
        }
    }
    __syncthreads();

    scp[t]       = (t < NBKT) ? hist[t] : 0;
    scp[t + 256] = (t + 256 < NBKT) ? hist[t + 256] : 0;
    __syncthreads();
    for (int d = 1; d < 512; d <<= 1) {
        int i1 = t, i2 = t + 256;
        int v1 = scp[i1]; if (i1 >= d) v1 += scp[i1 - d];
        int v2 = scp[i2]; if (i2 >= d) v2 += scp[i2 - d];
        __syncthreads();
        scp[i1] = v1; scp[i2] = v2;
        __syncthreads();
    }
    {
        int ex1 = scp[t] - ((t < NBKT) ? hist[t] : 0);
        int ex2 = scp[t + 256] - ((t + 256 < NBKT) ? hist[t + 256] : 0);
        __syncthreads();
        scp[t] = ex1; scp[t + 256] = ex2;
    }
    for (int b = t; b < NBKT; b += 256) runbase[b] = atomicAdd(&gnext[b], hist[b]);
    __syncthreads();

    #pragma unroll
    for (int i = 0; i < EPB / 256; ++i) {
        if (myc[i] >= 0) {
            int e = e0 + i * 256 + t;
            int b = myc[i] >> 8;
            int cl = myc[i] & 255;
            stage[scp[b] + myr[i]] = (cl << 24) | e;
        }
    }
    __syncthreads();

    for (int slot = t; slot < nvalid; slot += 256) {
        int lo = 0, hi = NBKT - 1;
        while (lo < hi) {
            int mid = (lo + hi + 1) >> 1;
            if (scp[mid] <= slot) lo = mid; else hi = mid - 1;
        }
        int b = lo;
        int idx = runbase[b] + (slot - scp[b]);
        if (idx < BCAP) pairs[b * BCAP + idx] = stage[slot];
    }
}

// P2 + edge-MLP + mean fused: fine partition in LDS, then gather-RECOMPUTE.
// Messages are consumed exactly once -> compute them at the consumer.
__global__ __launch_bounds__(256) void p2_agg_kernel(
    const int* __restrict__ pairs, const int* __restrict__ gnext,
    const float* __restrict__ x, const int* __restrict__ ei,
    const float* __restrict__ ea,
    const half2_t* __restrict__ w1t, const float* __restrict__ b1,
    const half2_t* __restrict__ w2t, const float* __restrict__ b2,
    float* __restrict__ summed)
{
    __shared__ int ncnt[256];
    __shared__ int nstart[256];
    __shared__ int cur[256];
    __shared__ int pstage[BCAP];

    int t = threadIdx.x;
    int b = blockIdx.x;
    int m = gnext[b]; if (m > BCAP) m = BCAP;
    const int* pb = pairs + b * BCAP;

    ncnt[t] = 0;
    __syncthreads();
    for (int i = t; i < m; i += 256) {
        atomicAdd(&ncnt[(unsigned)pb[i] >> 24], 1);
    }
    __syncthreads();

    nstart[t] = ncnt[t];
    __syncthreads();
    for (int d = 1; d < 256; d <<= 1) {
        int v = nstart[t]; if (t >= d) v += nstart[t - d];
        __syncthreads();
        nstart[t] = v;
        __syncthreads();
    }
    {
        int ex = nstart[t] - ncnt[t];
        __syncthreads();
        nstart[t] = ex;
        __syncthreads();
    }
    cur[t] = nstart[t];
    __syncthreads();

    for (int i = t; i < m; i += 256) {
        unsigned p = (unsigned)pb[i];
        int r = atomicAdd(&cur[p >> 24], 1);
        pstage[r] = (int)(p & 0xFFFFFFu);
    }
    __syncthreads();

    // gather-recompute: 4 phases x (64 nodes x 4 lanes/node)
    #pragma clang loop unroll(disable)
    for (int phase = 0; phase < 4; ++phase) {
        int nl   = phase * 64 + (t >> 2);
        int part = t & 3;
        int d = ncnt[nl];
        int s = nstart[nl];

        float acc[HID];
        #pragma unroll
        for (int j = 0; j < HID; ++j) acc[j] = 0.f;

        #pragma clang loop unroll(disable)
        for (int i = part; i < d; i += 4) {
            int e = pstage[s + i];
            int row = ei[e];

            float in[FN + FE];
            #pragma unroll
            for (int k = 0; k < FN; ++k) in[k] = x[row * FN + k];
            const float2* ep = (const float2*)&ea[(size_t)e * FE];
            #pragma unroll
            for (int k = 0; k < FE / 2; ++k) {
                float2 v = ep[k];
                in[FN + 2*k] = v.x; in[FN + 2*k + 1] = v.y;
            }

            half2_t inp[7];
            #pragma unroll
            for (int kp = 0; kp < 6; ++kp) {
                half2_t v; v.x = (_Float16)in[2*kp]; v.y = (_Float16)in[2*kp+1];
                inp[kp] = v;
            }
            { half2_t v; v.x = (_Float16)in[12]; v.y = (_Float16)0.f; inp[6] = v; }

            float h[HID];
            #pragma unroll
            for (int j = 0; j < HID; ++j) {
                float a = b1[j];
                #pragma unroll
                for (int kp = 0; kp < 7; ++kp) a = fdot2(inp[kp], w1t[j * 7 + kp], a);
                h[j] = leaky(a);
            }

            half2_t hp[16];
            #pragma unroll
            for (int q = 0; q < 16; ++q) {
                half2_t v; v.x = (_Float16)h[2*q]; v.y = (_Float16)h[2*q+1];
                hp[q] = v;
            }

            #pragma unroll
            for (int j = 0; j < HID; ++j) {
                float a = b2[j];
                #pragma unroll
                for (int kp = 0; kp < 16; ++kp) a = fdot2(hp[kp], w2t[j * 16 + kp], a);
                acc[j] += a;
            }
        }

        // reduce across the 4 lanes of this node
        #pragma unroll
        for (int j = 0; j < HID; ++j) {
            float a = acc[j];
            a += __shfl_xor(a, 1);
            a += __shfl_xor(a, 2);
            acc[j] = a;
        }

        int node = b * 256 + nl;
        if (node < NN) {
            float inv = 1.f / fmaxf((float)d, 1.f);
            float4* op = (float4*)&summed[(size_t)node * HID];
            int c0 = part * 8;
            float4 v0 = make_float4(acc[c0+0]*inv, acc[c0+1]*inv, acc[c0+2]*inv, acc[c0+3]*inv);
            float4 v1 = make_float4(acc[c0+4]*inv, acc[c0+5]*inv, acc[c0+6]*inv, acc[c0+7]*inv);
            op[part * 2]     = v0;
            op[part * 2 + 1] = v1;
        }
    }
}

// ======================= fallback path (round-5, CSR) =====================

__global__ __launch_bounds__(256) void hist_kernel(const int* __restrict__ ei,
                                                   int* __restrict__ cnt)
{
    int e = blockIdx.x * 256 + threadIdx.x;
    if (e >= NE) return;
    atomicAdd(&cnt[ei[NE + e]], 1);
}

__global__ __launch_bounds__(1024) void scanA_kernel(const int* __restrict__ cnt,
                                                     int* __restrict__ off,
                                                     int* __restrict__ bsum)
{
    __shared__ int s[1024];
    int t = threadIdx.x;
    int i = blockIdx.x * 1024 + t;
    int v = (i < NN) ? cnt[i] : 0;
    s[t] = v;
    __syncthreads();
    for (int d = 1; d < 1024; d <<= 1) {
        int a = (t >= d) ? s[t - d] : 0;
        __syncthreads();
        s[t] += a;
        __syncthreads();
    }
    if (i < NN) off[i] = s[t] - v;
    if (t == 1023) bsum[blockIdx.x] = s[1023];
}

__global__ void scanB_kernel(int* __restrict__ bsum, int* __restrict__ boff)
{
    if (threadIdx.x == 0 && blockIdx.x == 0) {
        int run = 0;
        for (int b = 0; b < NB; ++b) { boff[b] = run; run += bsum[b]; }
    }
}

__global__ __launch_bounds__(256) void scanC_kernel(int* __restrict__ off,
                                                    const int* __restrict__ boff,
                                                    int* __restrict__ next)
{
    int i = blockIdx.x * 256 + threadIdx.x;
    if (i >= NN) return;
    int o = off[i] + boff[i >> 10];
    off[i] = o;
    next[i] = o;
}

__global__ __launch_bounds__(256) void edge_mlp_scatter_kernel(
    const float* __restrict__ x, const int* __restrict__ ei,
    const float* __restrict__ ea,
    const float* __restrict__ W1, const float* __restrict__ b1,
    const float* __restrict__ W2, const float* __restrict__ b2,
    int* __restrict__ next, __half* __restrict__ msg)
{
    int e = blockIdx.x * 256 + threadIdx.x;
    if (e >= NE) return;
    int row = ei[e];
    int col = ei[NE + e];
    int pos = atomicAdd(&next[col], 1);

    float in[FN + FE];
    #pragma unroll
    for (int k = 0; k < FN; ++k) in[k] = x[row * FN + k];
    const float2* ep = (const float2*)&ea[(size_t)e * FE];
    #pragma unroll
    for (int k = 0; k < FE / 2; ++k) {
        float2 v = ep[k];
        in[FN + 2*k] = v.x; in[FN + 2*k + 1] = v.y;
    }

    float h[HID];
    #pragma unroll
    for (int j = 0; j < HID; ++j) {
        float a = b1[j];
        #pragma unroll
        for (int k = 0; k < FN + FE; ++k) a = fmaf(in[k], W1[k * HID + j], a);
        h[j] = leaky(a);
    }
    float o[HID];
    #pragma unroll
    for (int j = 0; j < HID; ++j) {
        float a = b2[j];
        #pragma unroll
        for (int k = 0; k < HID; ++k) a = fmaf(h[k], W2[k * HID + j], a);
        o[j] = a;
    }

    __half2 hh[HID / 2];
    #pragma unroll
    for (int q = 0; q < HID / 2; ++q) hh[q] = __floats2half2_rn(o[2*q], o[2*q+1]);
    uint4* dst = (uint4*)(msg + (size_t)pos * HID);
    const uint4* src = (const uint4*)hh;
    #pragma unroll
    for (int q = 0; q < 4; ++q) dst[q] = src[q];
}

__global__ __launch_bounds__(256) void mean_csr_kernel(
    const __half* __restrict__ msg, const int* __restrict__ off,
    const int* __restrict__ cnt, float* __restrict__ summed)
{
    int gid = blockIdx.x * 256 + threadIdx.x;
    int node = gid >> 3;
    int lane = gid & 7;
    if (node >= NN) return;
    int t0 = off[node], d = cnt[node];

    float4 acc = make_float4(0.f, 0.f, 0.f, 0.f);
    const __half2* p = (const __half2*)(msg + (size_t)t0 * HID + lane * 4);
    for (int t = 0; t < d; ++t) {
        __half2 a = p[0], b = p[1];
        float2 fa = __half22float2(a), fb = __half22float2(b);
        acc.x += fa.x; acc.y += fa.y; acc.z += fb.x; acc.w += fb.y;
        p += HID / 2;
    }
    float inv = 1.f / fmaxf((float)d, 1.f);
    acc.x *= inv; acc.y *= inv; acc.z *= inv; acc.w *= inv;
    ((float4*)&summed[(size_t)node * HID])[lane] = acc;
}

// ======================= node MLP (shared) ================================

__global__ __launch_bounds__(256) void node_kernel(
    const float* __restrict__ x, const float* __restrict__ summed,
    const float* __restrict__ u,
    const int* __restrict__ batch,
    const float* __restrict__ W3, const float* __restrict__ b3,
    const float* __restrict__ W4, const float* __restrict__ b4,
    float* __restrict__ out)
{
    __shared__ __align__(16) float sW3[(FN + HID + FG) * HID];
    __shared__ __align__(16) float sW4[HID * FN];
    __shared__ __align__(16) float sb3[HID];
    __shared__ float sb4[FN];
    int tid = threadIdx.x;
    for (int i = tid; i < (FN + HID + FG) * HID; i += 256) sW3[i] = W3[i];
    for (int i = tid; i < HID * FN; i += 256) sW4[i] = W4[i];
    if (tid < HID) sb3[tid] = b3[tid];
    if (tid < FN) sb4[tid] = b4[tid];
    __syncthreads();

    int i = blockIdx.x * 256 + tid;
    if (i >= NN) return;

    float g[HID];
    #pragma unroll
    for (int jq = 0; jq < HID / 4; ++jq) {
        float4 bb = ((const float4*)sb3)[jq];
        g[4*jq+0] = bb.x; g[4*jq+1] = bb.y; g[4*jq+2] = bb.z; g[4*jq+3] = bb.w;
    }

    #pragma unroll
    for (int k = 0; k < FN; ++k) {
        float a = x[i * FN + k];
        const float4* wr = (const float4*)(sW3 + k * HID);
        #pragma unroll
        for (int jq = 0; jq < HID / 4; ++jq) {
            float4 w = wr[jq];
            g[4*jq+0] = fmaf(a, w.x, g[4*jq+0]);
            g[4*jq+1] = fmaf(a, w.y, g[4*jq+1]);
            g[4*jq+2] = fmaf(a, w.z, g[4*jq+2]);
            g[4*jq+3] = fmaf(a, w.w, g[4*jq+3]);
        }
    }

    const float4* sp = (const float4*)&summed[(size_t)i * HID];
    #pragma unroll
    for (int kq = 0; kq < HID / 4; ++kq) {
        float4 mvv = sp[kq];
        #pragma unroll
        for (int c = 0; c < 4; ++c) {
            float a = (c == 0) ? mvv.x : (c == 1) ? mvv.y : (c == 2) ? mvv.z : mvv.w;
            const float4* wr = (const float4*)(sW3 + (FN + 4*kq + c) * HID);
            #pragma unroll
            for (int jq = 0; jq < HID / 4; ++jq) {
                float4 w = wr[jq];
                g[4*jq+0] = fmaf(a, w.x, g[4*jq+0]);
                g[4*jq+1] = fmaf(a, w.y, g[4*jq+1]);
                g[4*jq+2] = fmaf(a, w.z, g[4*jq+2]);
                g[4*jq+3] = fmaf(a, w.w, g[4*jq+3]);
            }
        }
    }

    int b = batch[i];
    const float4* up = (const float4*)&u[(size_t)b * FG];
    #pragma unroll
    for (int kq = 0; kq < FG / 4; ++kq) {
        float4 uvv = up[kq];
        #pragma unroll
        for (int c = 0; c < 4; ++c) {
            float a = (c == 0) ? uvv.x : (c == 1) ? uvv.y : (c == 2) ? uvv.z : uvv.w;
            const float4* wr = (const float4*)(sW3 + (FN + HID + 4*kq + c) * HID);
            #pragma unroll
            for (int jq = 0; jq < HID / 4; ++jq) {
                float4 w = wr[jq];
                g[4*jq+0] = fmaf(a, w.x, g[4*jq+0]);
                g[4*jq+1] = fmaf(a, w.y, g[4*jq+1]);
                g[4*jq+2] = fmaf(a, w.z, g[4*jq+2]);
                g[4*jq+3] = fmaf(a, w.w, g[4*jq+3]);
            }
        }
    }

    #pragma unroll
    for (int j = 0; j < HID; ++j) g[j] = leaky(g[j]);

    #pragma unroll
    for (int j = 0; j < FN; ++j) {
        float acc = sb4[j];
        #pragma unroll
        for (int k = 0; k < HID; ++k) acc = fmaf(g[k], sW4[k * FN + j], acc);
        out[i * FN + j] = acc;
    }
}

// ======================= launch ===========================================

extern "C" void kernel_launch(void* const* d_in, const int* in_sizes, int n_in,
                              void* d_out, int out_size, void* d_ws, size_t ws_size,
                              hipStream_t stream)
{
    const float* x   = (const float*)d_in[0];
    const int*   ei  = (const int*)  d_in[1];
    const float* ea  = (const float*)d_in[2];
    const float* u   = (const float*)d_in[3];
    const int*   bat = (const int*)  d_in[4];
    const float* W1  = (const float*)d_in[5];
    const float* b1  = (const float*)d_in[6];
    const float* W2  = (const float*)d_in[7];
    const float* b2  = (const float*)d_in[8];
    const float* W3  = (const float*)d_in[9];
    const float* b3  = (const float*)d_in[10];
    const float* W4  = (const float*)d_in[11];
    const float* b4  = (const float*)d_in[12];
    float* out = (float*)d_out;

    // primary layout: gnext[400] | w1t[224] | w2t[512] | pairs[NBKT*BCAP] | summed[NN*HID]
    int*     gnext  = (int*)d_ws;
    half2_t* w1t    = (half2_t*)(gnext + 400);
    half2_t* w2t    = w1t + 224;
    int*     pairs  = (int*)(w2t + 512);
    float*   summed = (float*)(pairs + (size_t)NBKT * BCAP);
    size_t   need   = (size_t)((char*)(summed + (size_t)NN * HID) - (char*)d_ws);

    if (ws_size >= need) {
        hipMemsetAsync(gnext, 0, 400 * sizeof(int), stream);
        wprep_kernel<<<1, 256, 0, stream>>>(W1, W2, w1t, w2t);
        p1_partition_kernel<<<NBLK1, 256, 0, stream>>>(ei, gnext, pairs);
        p2_agg_kernel<<<NBKT, 256, 0, stream>>>(
            pairs, gnext, x, ei, ea, w1t, b1, w2t, b2, summed);
        node_kernel<<<(NN + 255) / 256, 256, 0, stream>>>(
            x, summed, u, bat, W3, b3, W4, b4, out);
        return;
    }

    // fallback layout (round-5): cnt|off|next|bsum|boff|summed|msg
    int*    fcnt    = (int*)d_ws;
    int*    foff    = fcnt + NN;
    int*    fnext   = foff + NN;
    int*    fbsum   = fnext + NN;
    int*    fboff   = fbsum + NB;
    float*  fsummed = (float*)(fboff + NB);
    __half* fmsg    = (__half*)(fsummed + (size_t)NN * HID);

    hipMemsetAsync(fcnt, 0, (size_t)NN * sizeof(int), stream);
    hist_kernel<<<(NE + 255) / 256, 256, 0, stream>>>(ei, fcnt);
    scanA_kernel<<<NB, 1024, 0, stream>>>(fcnt, foff, fbsum);
    scanB_kernel<<<1, 64, 0, stream>>>(fbsum, fboff);
    scanC_kernel<<<(NN + 255) / 256, 256, 0, stream>>>(foff, fboff, fnext);
    edge_mlp_scatter_kernel<<<(NE + 255) / 256, 256, 0, stream>>>(
        x, ei, ea, W1, b1, W2, b2, fnext, fmsg);
    mean_csr_kernel<<<(NN * 8 + 255) / 256, 256, 0, stream>>>(fmsg, foff, fcnt, fsummed);
    node_kernel<<<(NN + 255) / 256, 256, 0, stream>>>(
        x, fsummed, u, bat, W3, b3, W4, b4, out);
}

// Round 14
// 302.667 us; speedup vs baseline: 1.4483x; 1.4483x over previous
//
#include <hip/hip_runtime.h>
#include <hip/hip_fp16.h>

#define NN 100000
#define NE 3200000
#define FN 7
#define FE 6
#define FG 64
#define HID 32
#define EPB 4096                          // edges per P1 block
#define NBLK1 ((NE + EPB - 1) / EPB)      // 782
#define NBKT ((NN + 255) >> 8)            // 391 coarse buckets (256 nodes each)
#define BCAP 9000                         // per-bucket capacity (mean 8192 + 8.9 sigma)
#define NB ((NN + 1023) / 1024)           // fallback scan blocks

typedef _Float16 half2_t __attribute__((ext_vector_type(2)));
typedef float f32x4 __attribute__((ext_vector_type(4)));
typedef float f32x2 __attribute__((ext_vector_type(2)));
typedef f32x4 uf32x4 __attribute__((aligned(4)));   // 4B-aligned vector loads
typedef f32x2 uf32x2 __attribute__((aligned(4)));
typedef int i32x4 __attribute__((ext_vector_type(4)));

__device__ __forceinline__ float leaky(float v) { return v >= 0.f ? v : 0.01f * v; }

#if defined(__has_builtin) && __has_builtin(__builtin_amdgcn_fdot2)
__device__ __forceinline__ float fdot2(half2_t a, half2_t b, float c) {
    return __builtin_amdgcn_fdot2(a, b, c, false);
}
#else
__device__ __forceinline__ float fdot2(half2_t a, half2_t b, float c) {
    return fmaf((float)a.x, (float)b.x, fmaf((float)a.y, (float)b.y, c));
}
#endif

// ======================= weight prep (runs once per launch) ===============
__global__ __launch_bounds__(256) void wprep_kernel(
    const float* __restrict__ W1, const float* __restrict__ W2,
    half2_t* __restrict__ w1t, half2_t* __restrict__ w2t)
{
    int t = threadIdx.x;
    for (int i = t; i < 32 * 7; i += 256) {
        int j = i / 7, kp = i % 7;
        int k0 = 2 * kp, k1 = 2 * kp + 1;
        half2_t v;
        v.x = (_Float16)W1[k0 * HID + j];
        v.y = (k1 < FN + FE) ? (_Float16)W1[k1 * HID + j] : (_Float16)0.f;
        w1t[i] = v;
    }
    for (int i = t; i < 32 * 16; i += 256) {
        int j = i >> 4, kp = i & 15;
        half2_t v;
        v.x = (_Float16)W2[(2 * kp) * HID + j];
        v.y = (_Float16)W2[(2 * kp + 1) * HID + j];
        w2t[i] = v;
    }
}

// ======================= primary path =====================================

// P1: coarse partition; int4 col loads (4 consecutive edges per thread-chunk)
__global__ __launch_bounds__(256) void p1_partition_kernel(
    const int* __restrict__ ei, int* __restrict__ gnext, int* __restrict__ pairs)
{
    __shared__ int hist[NBKT];
    __shared__ int scp[512];
    __shared__ int runbase[NBKT];
    __shared__ int stage[EPB];

    int t = threadIdx.x;
    int e0 = blockIdx.x * EPB;
    int nvalid = NE - e0; if (nvalid > EPB) nvalid = EPB;

    for (int i = t; i < NBKT; i += 256) hist[i] = 0;
    __syncthreads();

    int myc[16];
    int myr[16];
    #pragma unroll
    for (int c = 0; c < 4; ++c) {
        int base = e0 + c * 1024 + t * 4;
        if (base + 3 < NE) {
            i32x4 cols = *(const i32x4*)&ei[NE + base];
            #pragma unroll
            for (int j = 0; j < 4; ++j) {
                int col = cols[j];
                myc[c * 4 + j] = col;
                myr[c * 4 + j] = atomicAdd(&hist[col >> 8], 1);
            }
        } else {
            #pragma unroll
            for (int j = 0; j < 4; ++j) {
                int e = base + j;
                myc[c * 4 + j] = -1;
                if (e < NE) {
                    int col = ei[NE + e];
                    myc[c * 4 + j] = col;
                    myr[c * 4 + j] = atomicAdd(&hist[col >> 8], 1);
                }
            }
        }
    }
    __syncthreads();

    scp[t]       = (t < NBKT) ? hist[t] : 0;
    scp[t + 256] = (t + 256 < NBKT) ? hist[t + 256] : 0;
    __syncthreads();
    for (int d = 1; d < 512; d <<= 1) {
        int i1 = t, i2 = t + 256;
        int v1 = scp[i1]; if (i1 >= d) v1 += scp[i1 - d];
        int v2 = scp[i2]; if (i2 >= d) v2 += scp[i2 - d];
        __syncthreads();
        scp[i1] = v1; scp[i2] = v2;
        __syncthreads();
    }
    {
        int ex1 = scp[t] - ((t < NBKT) ? hist[t] : 0);
        int ex2 = scp[t + 256] - ((t + 256 < NBKT) ? hist[t + 256] : 0);
        __syncthreads();
        scp[t] = ex1; scp[t + 256] = ex2;
    }
    for (int b = t; b < NBKT; b += 256) runbase[b] = atomicAdd(&gnext[b], hist[b]);
    __syncthreads();

    #pragma unroll
    for (int c = 0; c < 4; ++c) {
        #pragma unroll
        for (int j = 0; j < 4; ++j) {
            int idx = c * 4 + j;
            if (myc[idx] >= 0) {
                int e = e0 + c * 1024 + t * 4 + j;
                int b = myc[idx] >> 8;
                int cl = myc[idx] & 255;
                stage[scp[b] + myr[idx]] = (cl << 24) | e;
            }
        }
    }
    __syncthreads();

    for (int slot = t; slot < nvalid; slot += 256) {
        int lo = 0, hi = NBKT - 1;
        while (lo < hi) {
            int mid = (lo + hi + 1) >> 1;
            if (scp[mid] <= slot) lo = mid; else hi = mid - 1;
        }
        int b = lo;
        int idx = runbase[b] + (slot - scp[b]);
        if (idx < BCAP) pairs[b * BCAP + idx] = stage[slot];
    }
}

// edge MLP: straight-line 1 edge/thread, dot2 math, vectorized loads
__global__ __launch_bounds__(256) void edge_mlp_dot2_kernel(
    const float* __restrict__ x, const int* __restrict__ ei,
    const float* __restrict__ ea,
    const half2_t* __restrict__ w1t, const float* __restrict__ b1,
    const half2_t* __restrict__ w2t, const float* __restrict__ b2,
    __half* __restrict__ msg)
{
    int e = blockIdx.x * 256 + threadIdx.x;
    if (e >= NE) return;
    int row = ei[e];

    // x row: dwordx4 + dwordx2 + dword  (alignment 4 is legal on gfx9+)
    const float* xr = &x[row * FN];
    uf32x4 xa = *(const uf32x4*)xr;
    uf32x2 xb = *(const uf32x2*)(xr + 4);
    float  xc = xr[6];
    // ea row: dwordx4 + dwordx2 (8B aligned)
    const float* er = &ea[(size_t)e * FE];
    uf32x4 ya = *(const uf32x4*)er;
    uf32x2 yb = *(const uf32x2*)(er + 4);

    float in[FN + FE];
    in[0] = xa.x; in[1] = xa.y; in[2] = xa.z; in[3] = xa.w;
    in[4] = xb.x; in[5] = xb.y; in[6] = xc;
    in[7] = ya.x; in[8] = ya.y; in[9] = ya.z; in[10] = ya.w;
    in[11] = yb.x; in[12] = yb.y;

    half2_t inp[7];
    #pragma unroll
    for (int kp = 0; kp < 6; ++kp) {
        half2_t v; v.x = (_Float16)in[2*kp]; v.y = (_Float16)in[2*kp+1];
        inp[kp] = v;
    }
    { half2_t v; v.x = (_Float16)in[12]; v.y = (_Float16)0.f; inp[6] = v; }

    float h[HID];
    #pragma unroll
    for (int j = 0; j < HID; ++j) {
        float a = b1[j];
        #pragma unroll
        for (int kp = 0; kp < 7; ++kp) a = fdot2(inp[kp], w1t[j * 7 + kp], a);
        h[j] = leaky(a);
    }

    half2_t hp[16];
    #pragma unroll
    for (int q = 0; q < 16; ++q) {
        half2_t v; v.x = (_Float16)h[2*q]; v.y = (_Float16)h[2*q+1];
        hp[q] = v;
    }

    float o[HID];
    #pragma unroll
    for (int j = 0; j < HID; ++j) {
        float a = b2[j];
        #pragma unroll
        for (int kp = 0; kp < 16; ++kp) a = fdot2(hp[kp], w2t[j * 16 + kp], a);
        o[j] = a;
    }

    __half2 hh[HID / 2];
    #pragma unroll
    for (int q = 0; q < HID / 2; ++q) hh[q] = __floats2half2_rn(o[2*q], o[2*q+1]);
    uint4* dst = (uint4*)(msg + (size_t)e * HID);
    const uint4* src = (const uint4*)hh;
    #pragma unroll
    for (int q = 0; q < 4; ++q) dst[q] = src[q];
}

// P2+mean fused: fine partition in LDS, then gather (4 lanes x 16B per row)
__global__ __launch_bounds__(256) void p2_mean_kernel(
    const int* __restrict__ pairs, const int* __restrict__ gnext,
    const __half* __restrict__ msg, float* __restrict__ summed)
{
    __shared__ int ncnt[256];
    __shared__ int nstart[256];
    __shared__ int cur[256];
    __shared__ int pstage[BCAP];

    int t = threadIdx.x;
    int b = blockIdx.x;
    int m = gnext[b]; if (m > BCAP) m = BCAP;
    const int* pb = pairs + b * BCAP;

    ncnt[t] = 0;
    __syncthreads();
    for (int i = t; i < m; i += 256) {
        atomicAdd(&ncnt[(unsigned)pb[i] >> 24], 1);
    }
    __syncthreads();

    nstart[t] = ncnt[t];
    __syncthreads();
    for (int d = 1; d < 256; d <<= 1) {
        int v = nstart[t]; if (t >= d) v += nstart[t - d];
        __syncthreads();
        nstart[t] = v;
        __syncthreads();
    }
    {
        int ex = nstart[t] - ncnt[t];
        __syncthreads();
        nstart[t] = ex;
        __syncthreads();
    }
    cur[t] = nstart[t];
    __syncthreads();

    for (int i = t; i < m; i += 256) {
        unsigned p = (unsigned)pb[i];
        int r = atomicAdd(&cur[p >> 24], 1);
        pstage[r] = (int)(p & 0xFFFFFFu);
    }
    __syncthreads();

    // gather: 4 phases x (64 nodes x 4 lanes); lane reads 16B of the row
    #pragma unroll
    for (int phase = 0; phase < 4; ++phase) {
        int nl   = phase * 64 + (t >> 2);
        int lane = t & 3;
        int d = ncnt[nl];
        int s = nstart[nl];
        float4 alo = make_float4(0.f, 0.f, 0.f, 0.f);
        float4 ahi = make_float4(0.f, 0.f, 0.f, 0.f);
        #pragma unroll 4
        for (int i = 0; i < d; ++i) {
            int e = pstage[s + i];                        // LDS broadcast
            uint4 v = *(const uint4*)(msg + (size_t)e * HID + lane * 8);
            float2 f0 = __half22float2(*(__half2*)&v.x);
            float2 f1 = __half22float2(*(__half2*)&v.y);
            float2 f2 = __half22float2(*(__half2*)&v.z);
            float2 f3 = __half22float2(*(__half2*)&v.w);
            alo.x += f0.x; alo.y += f0.y; alo.z += f1.x; alo.w += f1.y;
            ahi.x += f2.x; ahi.y += f2.y; ahi.z += f3.x; ahi.w += f3.y;
        }
        int node = b * 256 + nl;
        if (node < NN) {
            float inv = 1.f / fmaxf((float)d, 1.f);
            alo.x *= inv; alo.y *= inv; alo.z *= inv; alo.w *= inv;
            ahi.x *= inv; ahi.y *= inv; ahi.z *= inv; ahi.w *= inv;
            float4* op = (float4*)&summed[(size_t)node * HID];
            op[lane * 2]     = alo;
            op[lane * 2 + 1] = ahi;
        }
    }
}

// ======================= fallback path (round-5, CSR) =====================

__global__ __launch_bounds__(256) void hist_kernel(const int* __restrict__ ei,
                                                   int* __restrict__ cnt)
{
    int e = blockIdx.x * 256 + threadIdx.x;
    if (e >= NE) return;
    atomicAdd(&cnt[ei[NE + e]], 1);
}

__global__ __launch_bounds__(1024) void scanA_kernel(const int* __restrict__ cnt,
                                                     int* __restrict__ off,
                                                     int* __restrict__ bsum)
{
    __shared__ int s[1024];
    int t = threadIdx.x;
    int i = blockIdx.x * 1024 + t;
    int v = (i < NN) ? cnt[i] : 0;
    s[t] = v;
    __syncthreads();
    for (int d = 1; d < 1024; d <<= 1) {
        int a = (t >= d) ? s[t - d] : 0;
        __syncthreads();
        s[t] += a;
        __syncthreads();
    }
    if (i < NN) off[i] = s[t] - v;
    if (t == 1023) bsum[blockIdx.x] = s[1023];
}

__global__ void scanB_kernel(int* __restrict__ bsum, int* __restrict__ boff)
{
    if (threadIdx.x == 0 && blockIdx.x == 0) {
        int run = 0;
        for (int b = 0; b < NB; ++b) { boff[b] = run; run += bsum[b]; }
    }
}

__global__ __launch_bounds__(256) void scanC_kernel(int* __restrict__ off,
                                                    const int* __restrict__ boff,
                                                    int* __restrict__ next)
{
    int i = blockIdx.x * 256 + threadIdx.x;
    if (i >= NN) return;
    int o = off[i] + boff[i >> 10];
    off[i] = o;
    next[i] = o;
}

__global__ __launch_bounds__(256) void edge_mlp_scatter_kernel(
    const float* __restrict__ x, const int* __restrict__ ei,
    const float* __restrict__ ea,
    const float* __restrict__ W1, const float* __restrict__ b1,
    const float* __restrict__ W2, const float* __restrict__ b2,
    int* __restrict__ next, __half* __restrict__ msg)
{
    int e = blockIdx.x * 256 + threadIdx.x;
    if (e >= NE) return;
    int row = ei[e];
    int col = ei[NE + e];
    int pos = atomicAdd(&next[col], 1);

    float in[FN + FE];
    #pragma unroll
    for (int k = 0; k < FN; ++k) in[k] = x[row * FN + k];
    const float2* ep = (const float2*)&ea[(size_t)e * FE];
    #pragma unroll
    for (int k = 0; k < FE / 2; ++k) {
        float2 v = ep[k];
        in[FN + 2*k] = v.x; in[FN + 2*k + 1] = v.y;
    }

    float h[HID];
    #pragma unroll
    for (int j = 0; j < HID; ++j) {
        float a = b1[j];
        #pragma unroll
        for (int k = 0; k < FN + FE; ++k) a = fmaf(in[k], W1[k * HID + j], a);
        h[j] = leaky(a);
    }
    float o[HID];
    #pragma unroll
    for (int j = 0; j < HID; ++j) {
        float a = b2[j];
        #pragma unroll
        for (int k = 0; k < HID; ++k) a = fmaf(h[k], W2[k * HID + j], a);
        o[j] = a;
    }

    __half2 hh[HID / 2];
    #pragma unroll
    for (int q = 0; q < HID / 2; ++q) hh[q] = __floats2half2_rn(o[2*q], o[2*q+1]);
    uint4* dst = (uint4*)(msg + (size_t)pos * HID);
    const uint4* src = (const uint4*)hh;
    #pragma unroll
    for (int q = 0; q < 4; ++q) dst[q] = src[q];
}

__global__ __launch_bounds__(256) void mean_csr_kernel(
    const __half* __restrict__ msg, const int* __restrict__ off,
    const int* __restrict__ cnt, float* __restrict__ summed)
{
    int gid = blockIdx.x * 256 + threadIdx.x;
    int node = gid >> 3;
    int lane = gid & 7;
    if (node >= NN) return;
    int t0 = off[node], d = cnt[node];

    float4 acc = make_float4(0.f, 0.f, 0.f, 0.f);
    const __half2* p = (const __half2*)(msg + (size_t)t0 * HID + lane * 4);
    for (int t = 0; t < d; ++t) {
        __half2 a = p[0], b = p[1];
        float2 fa = __half22float2(a), fb = __half22float2(b);
        acc.x += fa.x; acc.y += fa.y; acc.z += fb.x; acc.w += fb.y;
        p += HID / 2;
    }
    float inv = 1.f / fmaxf((float)d, 1.f);
    acc.x *= inv; acc.y *= inv; acc.z *= inv; acc.w *= inv;
    ((float4*)&summed[(size_t)node * HID])[lane] = acc;
}

// ======================= node MLP (shared) ================================

__global__ __launch_bounds__(256) void node_kernel(
    const float* __restrict__ x, const float* __restrict__ summed,
    const float* __restrict__ u,
    const int* __restrict__ batch,
    const float* __restrict__ W3, const float* __restrict__ b3,
    const float* __restrict__ W4, const float* __restrict__ b4,
    float* __restrict__ out)
{
    __shared__ __align__(16) float sW3[(FN + HID + FG) * HID];
    __shared__ __align__(16) float sW4[HID * FN];
    __shared__ __align__(16) float sb3[HID];
    __shared__ float sb4[FN];
    int tid = threadIdx.x;
    for (int i = tid; i < (FN + HID + FG) * HID; i += 256) sW3[i] = W3[i];
    for (int i = tid; i < HID * FN; i += 256) sW4[i] = W4[i];
    if (tid < HID) sb3[tid] = b3[tid];
    if (tid < FN) sb4[tid] = b4[tid];
    __syncthreads();

    int i = blockIdx.x * 256 + tid;
    if (i >= NN) return;

    float g[HID];
    #pragma unroll
    for (int jq = 0; jq < HID / 4; ++jq) {
        float4 bb = ((const float4*)sb3)[jq];
        g[4*jq+0] = bb.x; g[4*jq+1] = bb.y; g[4*jq+2] = bb.z; g[4*jq+3] = bb.w;
    }

    #pragma unroll
    for (int k = 0; k < FN; ++k) {
        float a = x[i * FN + k];
        const float4* wr = (const float4*)(sW3 + k * HID);
        #pragma unroll
        for (int jq = 0; jq < HID / 4; ++jq) {
            float4 w = wr[jq];
            g[4*jq+0] = fmaf(a, w.x, g[4*jq+0]);
            g[4*jq+1] = fmaf(a, w.y, g[4*jq+1]);
            g[4*jq+2] = fmaf(a, w.z, g[4*jq+2]);
            g[4*jq+3] = fmaf(a, w.w, g[4*jq+3]);
        }
    }

    const float4* sp = (const float4*)&summed[(size_t)i * HID];
    #pragma unroll
    for (int kq = 0; kq < HID / 4; ++kq) {
        float4 mvv = sp[kq];
        #pragma unroll
        for (int c = 0; c < 4; ++c) {
            float a = (c == 0) ? mvv.x : (c == 1) ? mvv.y : (c == 2) ? mvv.z : mvv.w;
            const float4* wr = (const float4*)(sW3 + (FN + 4*kq + c) * HID);
            #pragma unroll
            for (int jq = 0; jq < HID / 4; ++jq) {
                float4 w = wr[jq];
                g[4*jq+0] = fmaf(a, w.x, g[4*jq+0]);
                g[4*jq+1] = fmaf(a, w.y, g[4*jq+1]);
                g[4*jq+2] = fmaf(a, w.z, g[4*jq+2]);
                g[4*jq+3] = fmaf(a, w.w, g[4*jq+3]);
            }
        }
    }

    int b = batch[i];
    const float4* up = (const float4*)&u[(size_t)b * FG];
    #pragma unroll
    for (int kq = 0; kq < FG / 4; ++kq) {
        float4 uvv = up[kq];
        #pragma unroll
        for (int c = 0; c < 4; ++c) {
            float a = (c == 0) ? uvv.x : (c == 1) ? uvv.y : (c == 2) ? uvv.z : uvv.w;
            const float4* wr = (const float4*)(sW3 + (FN + HID + 4*kq + c) * HID);
            #pragma unroll
            for (int jq = 0; jq < HID / 4; ++jq) {
                float4 w = wr[jq];
                g[4*jq+0] = fmaf(a, w.x, g[4*jq+0]);
                g[4*jq+1] = fmaf(a, w.y, g[4*jq+1]);
                g[4*jq+2] = fmaf(a, w.z, g[4*jq+2]);
                g[4*jq+3] = fmaf(a, w.w, g[4*jq+3]);
            }
        }
    }

    #pragma unroll
    for (int j = 0; j < HID; ++j) g[j] = leaky(g[j]);

    #pragma unroll
    for (int j = 0; j < FN; ++j) {
        float acc = sb4[j];
        #pragma unroll
        for (int k = 0; k < HID; ++k) acc = fmaf(g[k], sW4[k * FN + j], acc);
        out[i * FN + j] = acc;
    }
}

// ======================= launch ===========================================

extern "C" void kernel_launch(void* const* d_in, const int* in_sizes, int n_in,
                              void* d_out, int out_size, void* d_ws, size_t ws_size,
                              hipStream_t stream)
{
    const float* x   = (const float*)d_in[0];
    const int*   ei  = (const int*)  d_in[1];
    const float* ea  = (const float*)d_in[2];
    const float* u   = (const float*)d_in[3];
    const int*   bat = (const int*)  d_in[4];
    const float* W1  = (const float*)d_in[5];
    const float* b1  = (const float*)d_in[6];
    const float* W2  = (const float*)d_in[7];
    const float* b2  = (const float*)d_in[8];
    const float* W3  = (const float*)d_in[9];
    const float* b3  = (const float*)d_in[10];
    const float* W4  = (const float*)d_in[11];
    const float* b4  = (const float*)d_in[12];
    float* out = (float*)d_out;

    // primary layout: gnext[400] | w1t[224] | w2t[512] | pairs[NBKT*BCAP] |
    //                 summed[NN*HID f32] | msg[NE*HID f16]
    int*     gnext  = (int*)d_ws;
    half2_t* w1t    = (half2_t*)(gnext + 400);
    half2_t* w2t    = w1t + 224;
    int*     pairs  = (int*)(w2t + 512);
    float*   summed = (float*)(pairs + (size_t)NBKT * BCAP);
    __half*  msg    = (__half*)(summed + (size_t)NN * HID);
    size_t   need   = (size_t)((char*)(msg + (size_t)NE * HID) - (char*)d_ws);

    if (ws_size >= need) {
        hipMemsetAsync(gnext, 0, 400 * sizeof(int), stream);
        wprep_kernel<<<1, 256, 0, stream>>>(W1, W2, w1t, w2t);
        p1_partition_kernel<<<NBLK1, 256, 0, stream>>>(ei, gnext, pairs);
        edge_mlp_dot2_kernel<<<(NE + 255) / 256, 256, 0, stream>>>(
            x, ei, ea, w1t, b1, w2t, b2, msg);
        p2_mean_kernel<<<NBKT, 256, 0, stream>>>(pairs, gnext, msg, summed);
        node_kernel<<<(NN + 255) / 256, 256, 0, stream>>>(
            x, summed, u, bat, W3, b3, W4, b4, out);
        return;
    }

    // fallback layout (round-5): cnt|off|next|bsum|boff|summed|msg
    int*    fcnt    = (int*)d_ws;
    int*    foff    = fcnt + NN;
    int*    fnext   = foff + NN;
    int*    fbsum   = fnext + NN;
    int*    fboff   = fbsum + NB;
    float*  fsummed = (float*)(fboff + NB);
    __half* fmsg    = (__half*)(fsummed + (size_t)NN * HID);

    hipMemsetAsync(fcnt, 0, (size_t)NN * sizeof(int), stream);
    hist_kernel<<<(NE + 255) / 256, 256, 0, stream>>>(ei, fcnt);
    scanA_kernel<<<NB, 1024, 0, stream>>>(fcnt, foff, fbsum);
    scanB_kernel<<<1, 64, 0, stream>>>(fbsum, fboff);
    scanC_kernel<<<(NN + 255) / 256, 256, 0, stream>>>(foff, fboff, fnext);
    edge_mlp_scatter_kernel<<<(NE + 255) / 256, 256, 0, stream>>>(
        x, ei, ea, W1, b1, W2, b2, fnext, fmsg);
    mean_csr_kernel<<<(NN * 8 + 255) / 256, 256, 0, stream>>>(fmsg, foff, fcnt, fsummed);
    node_kernel<<<(NN + 255) / 256, 256, 0, stream>>>(
        x, fsummed, u, bat, W3, b3, W4, b4, out);
}

// Round 15
// 288.099 us; speedup vs baseline: 1.5215x; 1.0506x over previous
//
#include <hip/hip_runtime.h>
#include <hip/hip_fp16.h>

#define NN 100000
#define NE 3200000
#define FN 7
#define FE 6
#define FG 64
#define HID 32
#define EPB 4096                          // edges per P1 block
#define NBLK1 ((NE + EPB - 1) / EPB)      // 782
#define NBKT ((NN + 127) >> 7)            // 782 coarse buckets (128 nodes each)
#define BCAP 4600                         // per-bucket cap (mean 4096 + 7.9 sigma)
#define NB ((NN + 1023) / 1024)           // fallback scan blocks

typedef _Float16 half2_t __attribute__((ext_vector_type(2)));
typedef int i32x4 __attribute__((ext_vector_type(4)));

__device__ __forceinline__ float leaky(float v) { return v >= 0.f ? v : 0.01f * v; }

#if defined(__has_builtin) && __has_builtin(__builtin_amdgcn_fdot2)
__device__ __forceinline__ float fdot2(half2_t a, half2_t b, float c) {
    return __builtin_amdgcn_fdot2(a, b, c, false);
}
#else
__device__ __forceinline__ float fdot2(half2_t a, half2_t b, float c) {
    return fmaf((float)a.x, (float)b.x, fmaf((float)a.y, (float)b.y, c));
}
#endif

// ======================= weight prep (runs once per launch) ===============
__global__ __launch_bounds__(256) void wprep_kernel(
    const float* __restrict__ W1, const float* __restrict__ W2,
    half2_t* __restrict__ w1t, half2_t* __restrict__ w2t)
{
    int t = threadIdx.x;
    for (int i = t; i < 32 * 7; i += 256) {
        int j = i / 7, kp = i % 7;
        int k0 = 2 * kp, k1 = 2 * kp + 1;
        half2_t v;
        v.x = (_Float16)W1[k0 * HID + j];
        v.y = (k1 < FN + FE) ? (_Float16)W1[k1 * HID + j] : (_Float16)0.f;
        w1t[i] = v;
    }
    for (int i = t; i < 32 * 16; i += 256) {
        int j = i >> 4, kp = i & 15;
        half2_t v;
        v.x = (_Float16)W2[(2 * kp) * HID + j];
        v.y = (_Float16)W2[(2 * kp + 1) * HID + j];
        w2t[i] = v;
    }
}

// ======================= primary path =====================================

// P1: coarse partition into 782 buckets of 128 nodes; 1024-padded scan.
__global__ __launch_bounds__(256) void p1_partition_kernel(
    const int* __restrict__ ei, int* __restrict__ gnext, int* __restrict__ pairs)
{
    __shared__ int hist[NBKT];
    __shared__ int scp[1024];
    __shared__ int runbase[NBKT];
    __shared__ int stage[EPB];

    int t = threadIdx.x;
    int e0 = blockIdx.x * EPB;
    int nvalid = NE - e0; if (nvalid > EPB) nvalid = EPB;

    for (int i = t; i < NBKT; i += 256) hist[i] = 0;
    __syncthreads();

    int myc[16];
    int myr[16];
    #pragma unroll
    for (int c = 0; c < 4; ++c) {
        int base = e0 + c * 1024 + t * 4;
        if (base + 3 < NE) {
            i32x4 cols = *(const i32x4*)&ei[NE + base];
            #pragma unroll
            for (int j = 0; j < 4; ++j) {
                int col = cols[j];
                myc[c * 4 + j] = col;
                myr[c * 4 + j] = atomicAdd(&hist[col >> 7], 1);
            }
        } else {
            #pragma unroll
            for (int j = 0; j < 4; ++j) {
                int e = base + j;
                myc[c * 4 + j] = -1;
                if (e < NE) {
                    int col = ei[NE + e];
                    myc[c * 4 + j] = col;
                    myr[c * 4 + j] = atomicAdd(&hist[col >> 7], 1);
                }
            }
        }
    }
    __syncthreads();

    // inclusive Hillis-Steele over padded 1024, 4 slots per thread
    scp[t]       = (t < NBKT) ? hist[t] : 0;
    scp[t + 256] = (t + 256 < NBKT) ? hist[t + 256] : 0;
    scp[t + 512] = (t + 512 < NBKT) ? hist[t + 512] : 0;
    scp[t + 768] = (t + 768 < NBKT) ? hist[t + 768] : 0;
    __syncthreads();
    for (int d = 1; d < 1024; d <<= 1) {
        int v0 = scp[t];       if (t >= d)       v0 += scp[t - d];
        int v1 = scp[t + 256]; if (t + 256 >= d) v1 += scp[t + 256 - d];
        int v2 = scp[t + 512]; v2 += scp[t + 512 - d];   // t+512 >= 512 >= d
        int v3 = scp[t + 768]; v3 += scp[t + 768 - d];
        __syncthreads();
        scp[t] = v0; scp[t + 256] = v1; scp[t + 512] = v2; scp[t + 768] = v3;
        __syncthreads();
    }
    // convert to exclusive
    {
        int e0v = scp[t]       - ((t < NBKT) ? hist[t] : 0);
        int e1v = scp[t + 256] - ((t + 256 < NBKT) ? hist[t + 256] : 0);
        int e2v = scp[t + 512] - ((t + 512 < NBKT) ? hist[t + 512] : 0);
        int e3v = scp[t + 768] - ((t + 768 < NBKT) ? hist[t + 768] : 0);
        __syncthreads();
        scp[t] = e0v; scp[t + 256] = e1v; scp[t + 512] = e2v; scp[t + 768] = e3v;
        __syncthreads();
    }
    for (int b = t; b < NBKT; b += 256) runbase[b] = atomicAdd(&gnext[b], hist[b]);
    __syncthreads();

    #pragma unroll
    for (int c = 0; c < 4; ++c) {
        #pragma unroll
        for (int j = 0; j < 4; ++j) {
            int idx = c * 4 + j;
            if (myc[idx] >= 0) {
                int e = e0 + c * 1024 + t * 4 + j;
                int b = myc[idx] >> 7;
                int cl = myc[idx] & 127;
                stage[scp[b] + myr[idx]] = (cl << 24) | e;
            }
        }
    }
    __syncthreads();

    for (int slot = t; slot < nvalid; slot += 256) {
        int lo = 0, hi = NBKT - 1;
        while (lo < hi) {
            int mid = (lo + hi + 1) >> 1;
            if (scp[mid] <= slot) lo = mid; else hi = mid - 1;
        }
        int b = lo;
        int idx = runbase[b] + (slot - scp[b]);
        if (idx < BCAP) pairs[b * BCAP + idx] = stage[slot];
    }
}

// edge MLP: straight-line 1 edge/thread, dot2 math (unchanged from r14)
__global__ __launch_bounds__(256) void edge_mlp_dot2_kernel(
    const float* __restrict__ x, const int* __restrict__ ei,
    const float* __restrict__ ea,
    const half2_t* __restrict__ w1t, const float* __restrict__ b1,
    const half2_t* __restrict__ w2t, const float* __restrict__ b2,
    __half* __restrict__ msg)
{
    int e = blockIdx.x * 256 + threadIdx.x;
    if (e >= NE) return;
    int row = ei[e];

    float in[FN + FE];
    #pragma unroll
    for (int k = 0; k < FN; ++k) in[k] = x[row * FN + k];
    const float2* ep = (const float2*)&ea[(size_t)e * FE];
    #pragma unroll
    for (int k = 0; k < FE / 2; ++k) {
        float2 v = ep[k];
        in[FN + 2*k] = v.x; in[FN + 2*k + 1] = v.y;
    }

    half2_t inp[7];
    #pragma unroll
    for (int kp = 0; kp < 6; ++kp) {
        half2_t v; v.x = (_Float16)in[2*kp]; v.y = (_Float16)in[2*kp+1];
        inp[kp] = v;
    }
    { half2_t v; v.x = (_Float16)in[12]; v.y = (_Float16)0.f; inp[6] = v; }

    float h[HID];
    #pragma unroll
    for (int j = 0; j < HID; ++j) {
        float a = b1[j];
        #pragma unroll
        for (int kp = 0; kp < 7; ++kp) a = fdot2(inp[kp], w1t[j * 7 + kp], a);
        h[j] = leaky(a);
    }

    half2_t hp[16];
    #pragma unroll
    for (int q = 0; q < 16; ++q) {
        half2_t v; v.x = (_Float16)h[2*q]; v.y = (_Float16)h[2*q+1];
        hp[q] = v;
    }

    float o[HID];
    #pragma unroll
    for (int j = 0; j < HID; ++j) {
        float a = b2[j];
        #pragma unroll
        for (int kp = 0; kp < 16; ++kp) a = fdot2(hp[kp], w2t[j * 16 + kp], a);
        o[j] = a;
    }

    __half2 hh[HID / 2];
    #pragma unroll
    for (int q = 0; q < HID / 2; ++q) hh[q] = __floats2half2_rn(o[2*q], o[2*q+1]);
    uint4* dst = (uint4*)(msg + (size_t)e * HID);
    const uint4* src = (const uint4*)hh;
    #pragma unroll
    for (int q = 0; q < 4; ++q) dst[q] = src[q];
}

// P2+mean fused over 128-node buckets: partition in LDS, then gather.
__global__ __launch_bounds__(256) void p2_mean_kernel(
    const int* __restrict__ pairs, const int* __restrict__ gnext,
    const __half* __restrict__ msg, float* __restrict__ summed)
{
    __shared__ int ncnt[128];
    __shared__ int nstart[128];
    __shared__ int cur[128];
    __shared__ int pstage[BCAP];

    int t = threadIdx.x;
    int b = blockIdx.x;
    int m = gnext[b]; if (m > BCAP) m = BCAP;
    const int* pb = pairs + b * BCAP;

    if (t < 128) ncnt[t] = 0;
    __syncthreads();
    for (int i = t; i < m; i += 256) {
        atomicAdd(&ncnt[(unsigned)pb[i] >> 24], 1);
    }
    __syncthreads();

    // exclusive scan over 128 counters (threads 0..127)
    if (t < 128) nstart[t] = ncnt[t];
    __syncthreads();
    for (int d = 1; d < 128; d <<= 1) {
        int v = 0;
        if (t < 128) { v = nstart[t]; if (t >= d) v += nstart[t - d]; }
        __syncthreads();
        if (t < 128) nstart[t] = v;
        __syncthreads();
    }
    if (t < 128) {
        int ex = nstart[t] - ncnt[t];
        nstart[t] = ex;
        cur[t] = ex;
    }
    __syncthreads();

    for (int i = t; i < m; i += 256) {
        unsigned p = (unsigned)pb[i];
        int r = atomicAdd(&cur[p >> 24], 1);
        pstage[r] = (int)(p & 0xFFFFFFu);
    }
    __syncthreads();

    // gather: 2 phases x (64 nodes x 4 lanes); lane reads 16B of the row
    #pragma unroll
    for (int phase = 0; phase < 2; ++phase) {
        int nl   = phase * 64 + (t >> 2);
        int lane = t & 3;
        int d = ncnt[nl];
        int s = nstart[nl];
        float4 alo = make_float4(0.f, 0.f, 0.f, 0.f);
        float4 ahi = make_float4(0.f, 0.f, 0.f, 0.f);
        #pragma unroll 4
        for (int i = 0; i < d; ++i) {
            int e = pstage[s + i];                        // LDS broadcast
            uint4 v = *(const uint4*)(msg + (size_t)e * HID + lane * 8);
            float2 f0 = __half22float2(*(__half2*)&v.x);
            float2 f1 = __half22float2(*(__half2*)&v.y);
            float2 f2 = __half22float2(*(__half2*)&v.z);
            float2 f3 = __half22float2(*(__half2*)&v.w);
            alo.x += f0.x; alo.y += f0.y; alo.z += f1.x; alo.w += f1.y;
            ahi.x += f2.x; ahi.y += f2.y; ahi.z += f3.x; ahi.w += f3.y;
        }
        int node = b * 128 + nl;
        if (node < NN) {
            float inv = 1.f / fmaxf((float)d, 1.f);
            alo.x *= inv; alo.y *= inv; alo.z *= inv; alo.w *= inv;
            ahi.x *= inv; ahi.y *= inv; ahi.z *= inv; ahi.w *= inv;
            float4* op = (float4*)&summed[(size_t)node * HID];
            op[lane * 2]     = alo;
            op[lane * 2 + 1] = ahi;
        }
    }
}

// ======================= fallback path (round-5, CSR) =====================

__global__ __launch_bounds__(256) void hist_kernel(const int* __restrict__ ei,
                                                   int* __restrict__ cnt)
{
    int e = blockIdx.x * 256 + threadIdx.x;
    if (e >= NE) return;
    atomicAdd(&cnt[ei[NE + e]], 1);
}

__global__ __launch_bounds__(1024) void scanA_kernel(const int* __restrict__ cnt,
                                                     int* __restrict__ off,
                                                     int* __restrict__ bsum)
{
    __shared__ int s[1024];
    int t = threadIdx.x;
    int i = blockIdx.x * 1024 + t;
    int v = (i < NN) ? cnt[i] : 0;
    s[t] = v;
    __syncthreads();
    for (int d = 1; d < 1024; d <<= 1) {
        int a = (t >= d) ? s[t - d] : 0;
        __syncthreads();
        s[t] += a;
        __syncthreads();
    }
    if (i < NN) off[i] = s[t] - v;
    if (t == 1023) bsum[blockIdx.x] = s[1023];
}

__global__ void scanB_kernel(int* __restrict__ bsum, int* __restrict__ boff)
{
    if (threadIdx.x == 0 && blockIdx.x == 0) {
        int run = 0;
        for (int b = 0; b < NB; ++b) { boff[b] = run; run += bsum[b]; }
    }
}

__global__ __launch_bounds__(256) void scanC_kernel(int* __restrict__ off,
                                                    const int* __restrict__ boff,
                                                    int* __restrict__ next)
{
    int i = blockIdx.x * 256 + threadIdx.x;
    if (i >= NN) return;
    int o = off[i] + boff[i >> 10];
    off[i] = o;
    next[i] = o;
}

__global__ __launch_bounds__(256) void edge_mlp_scatter_kernel(
    const float* __restrict__ x, const int* __restrict__ ei,
    const float* __restrict__ ea,
    const float* __restrict__ W1, const float* __restrict__ b1,
    const float* __restrict__ W2, const float* __restrict__ b2,
    int* __restrict__ next, __half* __restrict__ msg)
{
    int e = blockIdx.x * 256 + threadIdx.x;
    if (e >= NE) return;
    int row = ei[e];
    int col = ei[NE + e];
    int pos = atomicAdd(&next[col], 1);

    float in[FN + FE];
    #pragma unroll
    for (int k = 0; k < FN; ++k) in[k] = x[row * FN + k];
    const float2* ep = (const float2*)&ea[(size_t)e * FE];
    #pragma unroll
    for (int k = 0; k < FE / 2; ++k) {
        float2 v = ep[k];
        in[FN + 2*k] = v.x; in[FN + 2*k + 1] = v.y;
    }

    float h[HID];
    #pragma unroll
    for (int j = 0; j < HID; ++j) {
        float a = b1[j];
        #pragma unroll
        for (int k = 0; k < FN + FE; ++k) a = fmaf(in[k], W1[k * HID + j], a);
        h[j] = leaky(a);
    }
    float o[HID];
    #pragma unroll
    for (int j = 0; j < HID; ++j) {
        float a = b2[j];
        #pragma unroll
        for (int k = 0; k < HID; ++k) a = fmaf(h[k], W2[k * HID + j], a);
        o[j] = a;
    }

    __half2 hh[HID / 2];
    #pragma unroll
    for (int q = 0; q < HID / 2; ++q) hh[q] = __floats2half2_rn(o[2*q], o[2*q+1]);
    uint4* dst = (uint4*)(msg + (size_t)pos * HID);
    const uint4* src = (const uint4*)hh;
    #pragma unroll
    for (int q = 0; q < 4; ++q) dst[q] = src[q];
}

__global__ __launch_bounds__(256) void mean_csr_kernel(
    const __half* __restrict__ msg, const int* __restrict__ off,
    const int* __restrict__ cnt, float* __restrict__ summed)
{
    int gid = blockIdx.x * 256 + threadIdx.x;
    int node = gid >> 3;
    int lane = gid & 7;
    if (node >= NN) return;
    int t0 = off[node], d = cnt[node];

    float4 acc = make_float4(0.f, 0.f, 0.f, 0.f);
    const __half2* p = (const __half2*)(msg + (size_t)t0 * HID + lane * 4);
    for (int t = 0; t < d; ++t) {
        __half2 a = p[0], b = p[1];
        float2 fa = __half22float2(a), fb = __half22float2(b);
        acc.x += fa.x; acc.y += fa.y; acc.z += fb.x; acc.w += fb.y;
        p += HID / 2;
    }
    float inv = 1.f / fmaxf((float)d, 1.f);
    acc.x *= inv; acc.y *= inv; acc.z *= inv; acc.w *= inv;
    ((float4*)&summed[(size_t)node * HID])[lane] = acc;
}

// ======================= node MLP (shared) ================================

__global__ __launch_bounds__(256) void node_kernel(
    const float* __restrict__ x, const float* __restrict__ summed,
    const float* __restrict__ u,
    const int* __restrict__ batch,
    const float* __restrict__ W3, const float* __restrict__ b3,
    const float* __restrict__ W4, const float* __restrict__ b4,
    float* __restrict__ out)
{
    __shared__ __align__(16) float sW3[(FN + HID + FG) * HID];
    __shared__ __align__(16) float sW4[HID * FN];
    __shared__ __align__(16) float sb3[HID];
    __shared__ float sb4[FN];
    int tid = threadIdx.x;
    for (int i = tid; i < (FN + HID + FG) * HID; i += 256) sW3[i] = W3[i];
    for (int i = tid; i < HID * FN; i += 256) sW4[i] = W4[i];
    if (tid < HID) sb3[tid] = b3[tid];
    if (tid < FN) sb4[tid] = b4[tid];
    __syncthreads();

    int i = blockIdx.x * 256 + tid;
    if (i >= NN) return;

    float g[HID];
    #pragma unroll
    for (int jq = 0; jq < HID / 4; ++jq) {
        float4 bb = ((const float4*)sb3)[jq];
        g[4*jq+0] = bb.x; g[4*jq+1] = bb.y; g[4*jq+2] = bb.z; g[4*jq+3] = bb.w;
    }

    #pragma unroll
    for (int k = 0; k < FN; ++k) {
        float a = x[i * FN + k];
        const float4* wr = (const float4*)(sW3 + k * HID);
        #pragma unroll
        for (int jq = 0; jq < HID / 4; ++jq) {
            float4 w = wr[jq];
            g[4*jq+0] = fmaf(a, w.x, g[4*jq+0]);
            g[4*jq+1] = fmaf(a, w.y, g[4*jq+1]);
            g[4*jq+2] = fmaf(a, w.z, g[4*jq+2]);
            g[4*jq+3] = fmaf(a, w.w, g[4*jq+3]);
        }
    }

    const float4* sp = (const float4*)&summed[(size_t)i * HID];
    #pragma unroll
    for (int kq = 0; kq < HID / 4; ++kq) {
        float4 mvv = sp[kq];
        #pragma unroll
        for (int c = 0; c < 4; ++c) {
            float a = (c == 0) ? mvv.x : (c == 1) ? mvv.y : (c == 2) ? mvv.z : mvv.w;
            const float4* wr = (const float4*)(sW3 + (FN + 4*kq + c) * HID);
            #pragma unroll
            for (int jq = 0; jq < HID / 4; ++jq) {
                float4 w = wr[jq];
                g[4*jq+0] = fmaf(a, w.x, g[4*jq+0]);
                g[4*jq+1] = fmaf(a, w.y, g[4*jq+1]);
                g[4*jq+2] = fmaf(a, w.z, g[4*jq+2]);
                g[4*jq+3] = fmaf(a, w.w, g[4*jq+3]);
            }
        }
    }

    int b = batch[i];
    const float4* up = (const float4*)&u[(size_t)b * FG];
    #pragma unroll
    for (int kq = 0; kq < FG / 4; ++kq) {
        float4 uvv = up[kq];
        #pragma unroll
        for (int c = 0; c < 4; ++c) {
            float a = (c == 0) ? uvv.x : (c == 1) ? uvv.y : (c == 2) ? uvv.z : uvv.w;
            const float4* wr = (const float4*)(sW3 + (FN + HID + 4*kq + c) * HID);
            #pragma unroll
            for (int jq = 0; jq < HID / 4; ++jq) {
                float4 w = wr[jq];
                g[4*jq+0] = fmaf(a, w.x, g[4*jq+0]);
                g[4*jq+1] = fmaf(a, w.y, g[4*jq+1]);
                g[4*jq+2] = fmaf(a, w.z, g[4*jq+2]);
                g[4*jq+3] = fmaf(a, w.w, g[4*jq+3]);
            }
        }
    }

    #pragma unroll
    for (int j = 0; j < HID; ++j) g[j] = leaky(g[j]);

    #pragma unroll
    for (int j = 0; j < FN; ++j) {
        float acc = sb4[j];
        #pragma unroll
        for (int k = 0; k < HID; ++k) acc = fmaf(g[k], sW4[k * FN + j], acc);
        out[i * FN + j] = acc;
    }
}

// ======================= launch ===========================================

extern "C" void kernel_launch(void* const* d_in, const int* in_sizes, int n_in,
                              void* d_out, int out_size, void* d_ws, size_t ws_size,
                              hipStream_t stream)
{
    const float* x   = (const float*)d_in[0];
    const int*   ei  = (const int*)  d_in[1];
    const float* ea  = (const float*)d_in[2];
    const float* u   = (const float*)d_in[3];
    const int*   bat = (const int*)  d_in[4];
    const float* W1  = (const float*)d_in[5];
    const float* b1  = (const float*)d_in[6];
    const float* W2  = (const float*)d_in[7];
    const float* b2  = (const float*)d_in[8];
    const float* W3  = (const float*)d_in[9];
    const float* b3  = (const float*)d_in[10];
    const float* W4  = (const float*)d_in[11];
    const float* b4  = (const float*)d_in[12];
    float* out = (float*)d_out;

    // primary layout: gnext[800] | w1t[224] | w2t[512] | pairs[NBKT*BCAP] |
    //                 summed[NN*HID f32] | msg[NE*HID f16]
    int*     gnext  = (int*)d_ws;
    half2_t* w1t    = (half2_t*)(gnext + 800);
    half2_t* w2t    = w1t + 224;
    int*     pairs  = (int*)(w2t + 512);
    float*   summed = (float*)(pairs + (size_t)NBKT * BCAP);
    __half*  msg    = (__half*)(summed + (size_t)NN * HID);
    size_t   need   = (size_t)((char*)(msg + (size_t)NE * HID) - (char*)d_ws);

    if (ws_size >= need) {
        hipMemsetAsync(gnext, 0, 800 * sizeof(int), stream);
        wprep_kernel<<<1, 256, 0, stream>>>(W1, W2, w1t, w2t);
        p1_partition_kernel<<<NBLK1, 256, 0, stream>>>(ei, gnext, pairs);
        edge_mlp_dot2_kernel<<<(NE + 255) / 256, 256, 0, stream>>>(
            x, ei, ea, w1t, b1, w2t, b2, msg);
        p2_mean_kernel<<<NBKT, 256, 0, stream>>>(pairs, gnext, msg, summed);
        node_kernel<<<(NN + 255) / 256, 256, 0, stream>>>(
            x, summed, u, bat, W3, b3, W4, b4, out);
        return;
    }

    // fallback layout (round-5): cnt|off|next|bsum|boff|summed|msg
    int*    fcnt    = (int*)d_ws;
    int*    foff    = fcnt + NN;
    int*    fnext   = foff + NN;
    int*    fbsum   = fnext + NN;
    int*    fboff   = fbsum + NB;
    float*  fsummed = (float*)(fboff + NB);
    __half* fmsg    = (__half*)(fsummed + (size_t)NN * HID);

    hipMemsetAsync(fcnt, 0, (size_t)NN * sizeof(int), stream);
    hist_kernel<<<(NE + 255) / 256, 256, 0, stream>>>(ei, fcnt);
    scanA_kernel<<<NB, 1024, 0, stream>>>(fcnt, foff, fbsum);
    scanB_kernel<<<1, 64, 0, stream>>>(fbsum, fboff);
    scanC_kernel<<<(NN + 255) / 256, 256, 0, stream>>>(foff, fboff, fnext);
    edge_mlp_scatter_kernel<<<(NE + 255) / 256, 256, 0, stream>>>(
        x, ei, ea, W1, b1, W2, b2, fnext, fmsg);
    mean_csr_kernel<<<(NN * 8 + 255) / 256, 256, 0, stream>>>(fmsg, foff, fcnt, fsummed);
    node_kernel<<<(NN + 255) / 256, 256, 0, stream>>>(
        x, fsummed, u, bat, W3, b3, W4, b4, out);
}

// Round 16
// 285.133 us; speedup vs baseline: 1.5373x; 1.0104x over previous
//
#include <hip/hip_runtime.h>
#include <hip/hip_fp16.h>

#define NN 100000
#define NE 3200000
#define FN 7
#define FE 6
#define FG 64
#define HID 32
#define EPB 4096                          // edges per P1 block
#define NBLK1 ((NE + EPB - 1) / EPB)      // 782
#define NBKT ((NN + 63) >> 6)             // 1563 coarse buckets (64 nodes each)
#define BCAP 2432                         // per-bucket cap (mean 2048 + 8.5 sigma)
#define NB ((NN + 1023) / 1024)           // fallback scan blocks

typedef _Float16 half2_t __attribute__((ext_vector_type(2)));
typedef int i32x4 __attribute__((ext_vector_type(4)));

__device__ __forceinline__ float leaky(float v) { return v >= 0.f ? v : 0.01f * v; }

#if defined(__has_builtin) && __has_builtin(__builtin_amdgcn_fdot2)
__device__ __forceinline__ float fdot2(half2_t a, half2_t b, float c) {
    return __builtin_amdgcn_fdot2(a, b, c, false);
}
#else
__device__ __forceinline__ float fdot2(half2_t a, half2_t b, float c) {
    return fmaf((float)a.x, (float)b.x, fmaf((float)a.y, (float)b.y, c));
}
#endif

// ======================= weight prep (runs once per launch) ===============
__global__ __launch_bounds__(256) void wprep_kernel(
    const float* __restrict__ W1, const float* __restrict__ W2,
    half2_t* __restrict__ w1t, half2_t* __restrict__ w2t)
{
    int t = threadIdx.x;
    for (int i = t; i < 32 * 7; i += 256) {
        int j = i / 7, kp = i % 7;
        int k0 = 2 * kp, k1 = 2 * kp + 1;
        half2_t v;
        v.x = (_Float16)W1[k0 * HID + j];
        v.y = (k1 < FN + FE) ? (_Float16)W1[k1 * HID + j] : (_Float16)0.f;
        w1t[i] = v;
    }
    for (int i = t; i < 32 * 16; i += 256) {
        int j = i >> 4, kp = i & 15;
        half2_t v;
        v.x = (_Float16)W2[(2 * kp) * HID + j];
        v.y = (_Float16)W2[(2 * kp + 1) * HID + j];
        w2t[i] = v;
    }
}

// ======================= primary path =====================================

// P1: coarse partition into 1563 buckets of 64 nodes; 2048-padded scan.
__global__ __launch_bounds__(256) void p1_partition_kernel(
    const int* __restrict__ ei, int* __restrict__ gnext, int* __restrict__ pairs)
{
    __shared__ int hist[NBKT];
    __shared__ int scp[2048];
    __shared__ int runbase[NBKT];
    __shared__ int stage[EPB];

    int t = threadIdx.x;
    int e0 = blockIdx.x * EPB;
    int nvalid = NE - e0; if (nvalid > EPB) nvalid = EPB;

    for (int i = t; i < NBKT; i += 256) hist[i] = 0;
    __syncthreads();

    int myc[16];
    int myr[16];
    #pragma unroll
    for (int c = 0; c < 4; ++c) {
        int base = e0 + c * 1024 + t * 4;
        if (base + 3 < NE) {
            i32x4 cols = *(const i32x4*)&ei[NE + base];
            #pragma unroll
            for (int j = 0; j < 4; ++j) {
                int col = cols[j];
                myc[c * 4 + j] = col;
                myr[c * 4 + j] = atomicAdd(&hist[col >> 6], 1);
            }
        } else {
            #pragma unroll
            for (int j = 0; j < 4; ++j) {
                int e = base + j;
                myc[c * 4 + j] = -1;
                if (e < NE) {
                    int col = ei[NE + e];
                    myc[c * 4 + j] = col;
                    myr[c * 4 + j] = atomicAdd(&hist[col >> 6], 1);
                }
            }
        }
    }
    __syncthreads();

    // inclusive Hillis-Steele over padded 2048, 8 slots per thread
    #pragma unroll
    for (int s = 0; s < 8; ++s) {
        int idx = t + s * 256;
        scp[idx] = (idx < NBKT) ? hist[idx] : 0;
    }
    __syncthreads();
    for (int d = 1; d < 2048; d <<= 1) {
        int v[8];
        #pragma unroll
        for (int s = 0; s < 8; ++s) {
            int idx = t + s * 256;
            v[s] = scp[idx];
            if (idx >= d) v[s] += scp[idx - d];
        }
        __syncthreads();
        #pragma unroll
        for (int s = 0; s < 8; ++s) scp[t + s * 256] = v[s];
        __syncthreads();
    }
    // convert to exclusive
    {
        int v[8];
        #pragma unroll
        for (int s = 0; s < 8; ++s) {
            int idx = t + s * 256;
            v[s] = scp[idx] - ((idx < NBKT) ? hist[idx] : 0);
        }
        __syncthreads();
        #pragma unroll
        for (int s = 0; s < 8; ++s) scp[t + s * 256] = v[s];
        __syncthreads();
    }
    for (int b = t; b < NBKT; b += 256) runbase[b] = atomicAdd(&gnext[b], hist[b]);
    __syncthreads();

    #pragma unroll
    for (int c = 0; c < 4; ++c) {
        #pragma unroll
        for (int j = 0; j < 4; ++j) {
            int idx = c * 4 + j;
            if (myc[idx] >= 0) {
                int e = e0 + c * 1024 + t * 4 + j;
                int b = myc[idx] >> 6;
                int cl = myc[idx] & 63;
                stage[scp[b] + myr[idx]] = (cl << 24) | e;
            }
        }
    }
    __syncthreads();

    for (int slot = t; slot < nvalid; slot += 256) {
        int lo = 0, hi = NBKT - 1;
        while (lo < hi) {
            int mid = (lo + hi + 1) >> 1;
            if (scp[mid] <= slot) lo = mid; else hi = mid - 1;
        }
        int b = lo;
        int idx = runbase[b] + (slot - scp[b]);
        if (idx < BCAP) pairs[b * BCAP + idx] = stage[slot];
    }
}

// edge MLP: straight-line 1 edge/thread, dot2 math (frozen: known-good)
__global__ __launch_bounds__(256) void edge_mlp_dot2_kernel(
    const float* __restrict__ x, const int* __restrict__ ei,
    const float* __restrict__ ea,
    const half2_t* __restrict__ w1t, const float* __restrict__ b1,
    const half2_t* __restrict__ w2t, const float* __restrict__ b2,
    __half* __restrict__ msg)
{
    int e = blockIdx.x * 256 + threadIdx.x;
    if (e >= NE) return;
    int row = ei[e];

    float in[FN + FE];
    #pragma unroll
    for (int k = 0; k < FN; ++k) in[k] = x[row * FN + k];
    const float2* ep = (const float2*)&ea[(size_t)e * FE];
    #pragma unroll
    for (int k = 0; k < FE / 2; ++k) {
        float2 v = ep[k];
        in[FN + 2*k] = v.x; in[FN + 2*k + 1] = v.y;
    }

    half2_t inp[7];
    #pragma unroll
    for (int kp = 0; kp < 6; ++kp) {
        half2_t v; v.x = (_Float16)in[2*kp]; v.y = (_Float16)in[2*kp+1];
        inp[kp] = v;
    }
    { half2_t v; v.x = (_Float16)in[12]; v.y = (_Float16)0.f; inp[6] = v; }

    float h[HID];
    #pragma unroll
    for (int j = 0; j < HID; ++j) {
        float a = b1[j];
        #pragma unroll
        for (int kp = 0; kp < 7; ++kp) a = fdot2(inp[kp], w1t[j * 7 + kp], a);
        h[j] = leaky(a);
    }

    half2_t hp[16];
    #pragma unroll
    for (int q = 0; q < 16; ++q) {
        half2_t v; v.x = (_Float16)h[2*q]; v.y = (_Float16)h[2*q+1];
        hp[q] = v;
    }

    float o[HID];
    #pragma unroll
    for (int j = 0; j < HID; ++j) {
        float a = b2[j];
        #pragma unroll
        for (int kp = 0; kp < 16; ++kp) a = fdot2(hp[kp], w2t[j * 16 + kp], a);
        o[j] = a;
    }

    __half2 hh[HID / 2];
    #pragma unroll
    for (int q = 0; q < HID / 2; ++q) hh[q] = __floats2half2_rn(o[2*q], o[2*q+1]);
    uint4* dst = (uint4*)(msg + (size_t)e * HID);
    const uint4* src = (const uint4*)hh;
    #pragma unroll
    for (int q = 0; q < 4; ++q) dst[q] = src[q];
}

// P2+mean fused over 64-node buckets: partition in LDS, then gather.
__global__ __launch_bounds__(256) void p2_mean_kernel(
    const int* __restrict__ pairs, const int* __restrict__ gnext,
    const __half* __restrict__ msg, float* __restrict__ summed)
{
    __shared__ int ncnt[64];
    __shared__ int nstart[64];
    __shared__ int cur[64];
    __shared__ int pstage[BCAP];

    int t = threadIdx.x;
    int b = blockIdx.x;
    int m = gnext[b]; if (m > BCAP) m = BCAP;
    const int* pb = pairs + b * BCAP;

    if (t < 64) ncnt[t] = 0;
    __syncthreads();
    for (int i = t; i < m; i += 256) {
        atomicAdd(&ncnt[(unsigned)pb[i] >> 24], 1);
    }
    __syncthreads();

    // exclusive scan over 64 counters (threads 0..63)
    if (t < 64) nstart[t] = ncnt[t];
    __syncthreads();
    for (int d = 1; d < 64; d <<= 1) {
        int v = 0;
        if (t < 64) { v = nstart[t]; if (t >= d) v += nstart[t - d]; }
        __syncthreads();
        if (t < 64) nstart[t] = v;
        __syncthreads();
    }
    if (t < 64) {
        int ex = nstart[t] - ncnt[t];
        nstart[t] = ex;
        cur[t] = ex;
    }
    __syncthreads();

    for (int i = t; i < m; i += 256) {
        unsigned p = (unsigned)pb[i];
        int r = atomicAdd(&cur[p >> 24], 1);
        pstage[r] = (int)(p & 0xFFFFFFu);
    }
    __syncthreads();

    // gather: 64 nodes x 4 lanes; lane reads 16B of each 64B msg row
    {
        int nl   = t >> 2;
        int lane = t & 3;
        int d = ncnt[nl];
        int s = nstart[nl];
        float4 alo = make_float4(0.f, 0.f, 0.f, 0.f);
        float4 ahi = make_float4(0.f, 0.f, 0.f, 0.f);
        #pragma unroll 4
        for (int i = 0; i < d; ++i) {
            int e = pstage[s + i];                        // LDS broadcast
            uint4 v = *(const uint4*)(msg + (size_t)e * HID + lane * 8);
            float2 f0 = __half22float2(*(__half2*)&v.x);
            float2 f1 = __half22float2(*(__half2*)&v.y);
            float2 f2 = __half22float2(*(__half2*)&v.z);
            float2 f3 = __half22float2(*(__half2*)&v.w);
            alo.x += f0.x; alo.y += f0.y; alo.z += f1.x; alo.w += f1.y;
            ahi.x += f2.x; ahi.y += f2.y; ahi.z += f3.x; ahi.w += f3.y;
        }
        int node = b * 64 + nl;
        if (node < NN) {
            float inv = 1.f / fmaxf((float)d, 1.f);
            alo.x *= inv; alo.y *= inv; alo.z *= inv; alo.w *= inv;
            ahi.x *= inv; ahi.y *= inv; ahi.z *= inv; ahi.w *= inv;
            float4* op = (float4*)&summed[(size_t)node * HID];
            op[lane * 2]     = alo;
            op[lane * 2 + 1] = ahi;
        }
    }
}

// ======================= fallback path (round-5, CSR) =====================

__global__ __launch_bounds__(256) void hist_kernel(const int* __restrict__ ei,
                                                   int* __restrict__ cnt)
{
    int e = blockIdx.x * 256 + threadIdx.x;
    if (e >= NE) return;
    atomicAdd(&cnt[ei[NE + e]], 1);
}

__global__ __launch_bounds__(1024) void scanA_kernel(const int* __restrict__ cnt,
                                                     int* __restrict__ off,
                                                     int* __restrict__ bsum)
{
    __shared__ int s[1024];
    int t = threadIdx.x;
    int i = blockIdx.x * 1024 + t;
    int v = (i < NN) ? cnt[i] : 0;
    s[t] = v;
    __syncthreads();
    for (int d = 1; d < 1024; d <<= 1) {
        int a = (t >= d) ? s[t - d] : 0;
        __syncthreads();
        s[t] += a;
        __syncthreads();
    }
    if (i < NN) off[i] = s[t] - v;
    if (t == 1023) bsum[blockIdx.x] = s[1023];
}

__global__ void scanB_kernel(int* __restrict__ bsum, int* __restrict__ boff)
{
    if (threadIdx.x == 0 && blockIdx.x == 0) {
        int run = 0;
        for (int b = 0; b < NB; ++b) { boff[b] = run; run += bsum[b]; }
    }
}

__global__ __launch_bounds__(256) void scanC_kernel(int* __restrict__ off,
                                                    const int* __restrict__ boff,
                                                    int* __restrict__ next)
{
    int i = blockIdx.x * 256 + threadIdx.x;
    if (i >= NN) return;
    int o = off[i] + boff[i >> 10];
    off[i] = o;
    next[i] = o;
}

__global__ __launch_bounds__(256) void edge_mlp_scatter_kernel(
    const float* __restrict__ x, const int* __restrict__ ei,
    const float* __restrict__ ea,
    const float* __restrict__ W1, const float* __restrict__ b1,
    const float* __restrict__ W2, const float* __restrict__ b2,
    int* __restrict__ next, __half* __restrict__ msg)
{
    int e = blockIdx.x * 256 + threadIdx.x;
    if (e >= NE) return;
    int row = ei[e];
    int col = ei[NE + e];
    int pos = atomicAdd(&next[col], 1);

    float in[FN + FE];
    #pragma unroll
    for (int k = 0; k < FN; ++k) in[k] = x[row * FN + k];
    const float2* ep = (const float2*)&ea[(size_t)e * FE];
    #pragma unroll
    for (int k = 0; k < FE / 2; ++k) {
        float2 v = ep[k];
        in[FN + 2*k] = v.x; in[FN + 2*k + 1] = v.y;
    }

    float h[HID];
    #pragma unroll
    for (int j = 0; j < HID; ++j) {
        float a = b1[j];
        #pragma unroll
        for (int k = 0; k < FN + FE; ++k) a = fmaf(in[k], W1[k * HID + j], a);
        h[j] = leaky(a);
    }
    float o[HID];
    #pragma unroll
    for (int j = 0; j < HID; ++j) {
        float a = b2[j];
        #pragma unroll
        for (int k = 0; k < HID; ++k) a = fmaf(h[k], W2[k * HID + j], a);
        o[j] = a;
    }

    __half2 hh[HID / 2];
    #pragma unroll
    for (int q = 0; q < HID / 2; ++q) hh[q] = __floats2half2_rn(o[2*q], o[2*q+1]);
    uint4* dst = (uint4*)(msg + (size_t)pos * HID);
    const uint4* src = (const uint4*)hh;
    #pragma unroll
    for (int q = 0; q < 4; ++q) dst[q] = src[q];
}

__global__ __launch_bounds__(256) void mean_csr_kernel(
    const __half* __restrict__ msg, const int* __restrict__ off,
    const int* __restrict__ cnt, float* __restrict__ summed)
{
    int gid = blockIdx.x * 256 + threadIdx.x;
    int node = gid >> 3;
    int lane = gid & 7;
    if (node >= NN) return;
    int t0 = off[node], d = cnt[node];

    float4 acc = make_float4(0.f, 0.f, 0.f, 0.f);
    const __half2* p = (const __half2*)(msg + (size_t)t0 * HID + lane * 4);
    for (int t = 0; t < d; ++t) {
        __half2 a = p[0], b = p[1];
        float2 fa = __half22float2(a), fb = __half22float2(b);
        acc.x += fa.x; acc.y += fa.y; acc.z += fb.x; acc.w += fb.y;
        p += HID / 2;
    }
    float inv = 1.f / fmaxf((float)d, 1.f);
    acc.x *= inv; acc.y *= inv; acc.z *= inv; acc.w *= inv;
    ((float4*)&summed[(size_t)node * HID])[lane] = acc;
}

// ======================= node MLP (shared) ================================

__global__ __launch_bounds__(256) void node_kernel(
    const float* __restrict__ x, const float* __restrict__ summed,
    const float* __restrict__ u,
    const int* __restrict__ batch,
    const float* __restrict__ W3, const float* __restrict__ b3,
    const float* __restrict__ W4, const float* __restrict__ b4,
    float* __restrict__ out)
{
    __shared__ __align__(16) float sW3[(FN + HID + FG) * HID];
    __shared__ __align__(16) float sW4[HID * FN];
    __shared__ __align__(16) float sb3[HID];
    __shared__ float sb4[FN];
    int tid = threadIdx.x;
    for (int i = tid; i < (FN + HID + FG) * HID; i += 256) sW3[i] = W3[i];
    for (int i = tid; i < HID * FN; i += 256) sW4[i] = W4[i];
    if (tid < HID) sb3[tid] = b3[tid];
    if (tid < FN) sb4[tid] = b4[tid];
    __syncthreads();

    int i = blockIdx.x * 256 + tid;
    if (i >= NN) return;

    float g[HID];
    #pragma unroll
    for (int jq = 0; jq < HID / 4; ++jq) {
        float4 bb = ((const float4*)sb3)[jq];
        g[4*jq+0] = bb.x; g[4*jq+1] = bb.y; g[4*jq+2] = bb.z; g[4*jq+3] = bb.w;
    }

    #pragma unroll
    for (int k = 0; k < FN; ++k) {
        float a = x[i * FN + k];
        const float4* wr = (const float4*)(sW3 + k * HID);
        #pragma unroll
        for (int jq = 0; jq < HID / 4; ++jq) {
            float4 w = wr[jq];
            g[4*jq+0] = fmaf(a, w.x, g[4*jq+0]);
            g[4*jq+1] = fmaf(a, w.y, g[4*jq+1]);
            g[4*jq+2] = fmaf(a, w.z, g[4*jq+2]);
            g[4*jq+3] = fmaf(a, w.w, g[4*jq+3]);
        }
    }

    const float4* sp = (const float4*)&summed[(size_t)i * HID];
    #pragma unroll
    for (int kq = 0; kq < HID / 4; ++kq) {
        float4 mvv = sp[kq];
        #pragma unroll
        for (int c = 0; c < 4; ++c) {
            float a = (c == 0) ? mvv.x : (c == 1) ? mvv.y : (c == 2) ? mvv.z : mvv.w;
            const float4* wr = (const float4*)(sW3 + (FN + 4*kq + c) * HID);
            #pragma unroll
            for (int jq = 0; jq < HID / 4; ++jq) {
                float4 w = wr[jq];
                g[4*jq+0] = fmaf(a, w.x, g[4*jq+0]);
                g[4*jq+1] = fmaf(a, w.y, g[4*jq+1]);
                g[4*jq+2] = fmaf(a, w.z, g[4*jq+2]);
                g[4*jq+3] = fmaf(a, w.w, g[4*jq+3]);
            }
        }
    }

    int b = batch[i];
    const float4* up = (const float4*)&u[(size_t)b * FG];
    #pragma unroll
    for (int kq = 0; kq < FG / 4; ++kq) {
        float4 uvv = up[kq];
        #pragma unroll
        for (int c = 0; c < 4; ++c) {
            float a = (c == 0) ? uvv.x : (c == 1) ? uvv.y : (c == 2) ? uvv.z : uvv.w;
            const float4* wr = (const float4*)(sW3 + (FN + HID + 4*kq + c) * HID);
            #pragma unroll
            for (int jq = 0; jq < HID / 4; ++jq) {
                float4 w = wr[jq];
                g[4*jq+0] = fmaf(a, w.x, g[4*jq+0]);
                g[4*jq+1] = fmaf(a, w.y, g[4*jq+1]);
                g[4*jq+2] = fmaf(a, w.z, g[4*jq+2]);
                g[4*jq+3] = fmaf(a, w.w, g[4*jq+3]);
            }
        }
    }

    #pragma unroll
    for (int j = 0; j < HID; ++j) g[j] = leaky(g[j]);

    #pragma unroll
    for (int j = 0; j < FN; ++j) {
        float acc = sb4[j];
        #pragma unroll
        for (int k = 0; k < HID; ++k) acc = fmaf(g[k], sW4[k * FN + j], acc);
        out[i * FN + j] = acc;
    }
}

// ======================= launch ===========================================

extern "C" void kernel_launch(void* const* d_in, const int* in_sizes, int n_in,
                              void* d_out, int out_size, void* d_ws, size_t ws_size,
                              hipStream_t stream)
{
    const float* x   = (const float*)d_in[0];
    const int*   ei  = (const int*)  d_in[1];
    const float* ea  = (const float*)d_in[2];
    const float* u   = (const float*)d_in[3];
    const int*   bat = (const int*)  d_in[4];
    const float* W1  = (const float*)d_in[5];
    const float* b1  = (const float*)d_in[6];
    const float* W2  = (const float*)d_in[7];
    const float* b2  = (const float*)d_in[8];
    const float* W3  = (const float*)d_in[9];
    const float* b3  = (const float*)d_in[10];
    const float* W4  = (const float*)d_in[11];
    const float* b4  = (const float*)d_in[12];
    float* out = (float*)d_out;

    // primary layout: gnext[1600] | w1t[224] | w2t[512] | pairs[NBKT*BCAP] |
    //                 summed[NN*HID f32] | msg[NE*HID f16]
    int*     gnext  = (int*)d_ws;
    half2_t* w1t    = (half2_t*)(gnext + 1600);
    half2_t* w2t    = w1t + 224;
    int*     pairs  = (int*)(w2t + 512);
    float*   summed = (float*)(pairs + (size_t)NBKT * BCAP);
    __half*  msg    = (__half*)(summed + (size_t)NN * HID);
    size_t   need   = (size_t)((char*)(msg + (size_t)NE * HID) - (char*)d_ws);

    if (ws_size >= need) {
        hipMemsetAsync(gnext, 0, 1600 * sizeof(int), stream);
        wprep_kernel<<<1, 256, 0, stream>>>(W1, W2, w1t, w2t);
        p1_partition_kernel<<<NBLK1, 256, 0, stream>>>(ei, gnext, pairs);
        edge_mlp_dot2_kernel<<<(NE + 255) / 256, 256, 0, stream>>>(
            x, ei, ea, w1t, b1, w2t, b2, msg);
        p2_mean_kernel<<<NBKT, 256, 0, stream>>>(pairs, gnext, msg, summed);
        node_kernel<<<(NN + 255) / 256, 256, 0, stream>>>(
            x, summed, u, bat, W3, b3, W4, b4, out);
        return;
    }

    // fallback layout (round-5): cnt|off|next|bsum|boff|summed|msg
    int*    fcnt    = (int*)d_ws;
    int*    foff    = fcnt + NN;
    int*    fnext   = foff + NN;
    int*    fbsum   = fnext + NN;
    int*    fboff   = fbsum + NB;
    float*  fsummed = (float*)(fboff + NB);
    __half* fmsg    = (__half*)(fsummed + (size_t)NN * HID);

    hipMemsetAsync(fcnt, 0, (size_t)NN * sizeof(int), stream);
    hist_kernel<<<(NE + 255) / 256, 256, 0, stream>>>(ei, fcnt);
    scanA_kernel<<<NB, 1024, 0, stream>>>(fcnt, foff, fbsum);
    scanB_kernel<<<1, 64, 0, stream>>>(fbsum, fboff);
    scanC_kernel<<<(NN + 255) / 256, 256, 0, stream>>>(foff, fboff, fnext);
    edge_mlp_scatter_kernel<<<(NE + 255) / 256, 256, 0, stream>>>(
        x, ei, ea, W1, b1, W2, b2, fnext, fmsg);
    mean_csr_kernel<<<(NN * 8 + 255) / 256, 256, 0, stream>>>(fmsg, foff, fcnt, fsummed);
    node_kernel<<<(NN + 255) / 256, 256, 0, stream>>>(
        x, fsummed, u, bat, W3, b3, W4, b4, out);
}

// Round 17
// 245.045 us; speedup vs baseline: 1.7889x; 1.1636x over previous
//
#include <hip/hip_runtime.h>
#include <hip/hip_fp16.h>

#define NN 100000
#define NE 3200000
#define FN 7
#define FE 6
#define FG 64
#define HID 32
#define EPB 4096                          // edges per P1 block
#define NBLK1 ((NE + EPB - 1) / EPB)      // 782
#define NBKT ((NN + 63) >> 6)             // 1563 coarse buckets (64 nodes each)
#define BCAP 2432                         // per-bucket cap (mean 2048 + 8.5 sigma)
#define NB ((NN + 1023) / 1024)           // fallback scan blocks

typedef int i32x4 __attribute__((ext_vector_type(4)));
typedef _Float16 f16x8 __attribute__((ext_vector_type(8)));
typedef float f32x4 __attribute__((ext_vector_type(4)));

__device__ __forceinline__ float leaky(float v) { return v >= 0.f ? v : 0.01f * v; }

// ======================= weight prep: MFMA B-fragments ====================
// B-fragment layout for mfma_f32_16x16x32_f16: lane l holds
// B[k=(l>>4)*8+i][col = f*16 + (l&15)], i=0..7.  w1 zero-padded past k=12.
__global__ __launch_bounds__(256) void wprep_kernel(
    const float* __restrict__ W1, const float* __restrict__ W2,
    _Float16* __restrict__ w1f, _Float16* __restrict__ w2f)
{
    int t = threadIdx.x;
    for (int idx = t; idx < 1024; idx += 256) {
        int f = idx >> 9, rem = idx & 511, l = rem >> 3, i = rem & 7;
        int k = (l >> 4) * 8 + i, col = f * 16 + (l & 15);
        w1f[idx] = (k < FN + FE) ? (_Float16)W1[k * HID + col] : (_Float16)0.f;
        w2f[idx] = (_Float16)W2[k * HID + col];
    }
}

// ======================= primary path =====================================

// P1: coarse partition into 1563 buckets of 64 nodes (unchanged from r16)
__global__ __launch_bounds__(256) void p1_partition_kernel(
    const int* __restrict__ ei, int* __restrict__ gnext, int* __restrict__ pairs)
{
    __shared__ int hist[NBKT];
    __shared__ int scp[2048];
    __shared__ int runbase[NBKT];
    __shared__ int stage[EPB];

    int t = threadIdx.x;
    int e0 = blockIdx.x * EPB;
    int nvalid = NE - e0; if (nvalid > EPB) nvalid = EPB;

    for (int i = t; i < NBKT; i += 256) hist[i] = 0;
    __syncthreads();

    int myc[16];
    int myr[16];
    #pragma unroll
    for (int c = 0; c < 4; ++c) {
        int base = e0 + c * 1024 + t * 4;
        if (base + 3 < NE) {
            i32x4 cols = *(const i32x4*)&ei[NE + base];
            #pragma unroll
            for (int j = 0; j < 4; ++j) {
                int col = cols[j];
                myc[c * 4 + j] = col;
                myr[c * 4 + j] = atomicAdd(&hist[col >> 6], 1);
            }
        } else {
            #pragma unroll
            for (int j = 0; j < 4; ++j) {
                int e = base + j;
                myc[c * 4 + j] = -1;
                if (e < NE) {
                    int col = ei[NE + e];
                    myc[c * 4 + j] = col;
                    myr[c * 4 + j] = atomicAdd(&hist[col >> 6], 1);
                }
            }
        }
    }
    __syncthreads();

    #pragma unroll
    for (int s = 0; s < 8; ++s) {
        int idx = t + s * 256;
        scp[idx] = (idx < NBKT) ? hist[idx] : 0;
    }
    __syncthreads();
    for (int d = 1; d < 2048; d <<= 1) {
        int v[8];
        #pragma unroll
        for (int s = 0; s < 8; ++s) {
            int idx = t + s * 256;
            v[s] = scp[idx];
            if (idx >= d) v[s] += scp[idx - d];
        }
        __syncthreads();
        #pragma unroll
        for (int s = 0; s < 8; ++s) scp[t + s * 256] = v[s];
        __syncthreads();
    }
    {
        int v[8];
        #pragma unroll
        for (int s = 0; s < 8; ++s) {
            int idx = t + s * 256;
            v[s] = scp[idx] - ((idx < NBKT) ? hist[idx] : 0);
        }
        __syncthreads();
        #pragma unroll
        for (int s = 0; s < 8; ++s) scp[t + s * 256] = v[s];
        __syncthreads();
    }
    for (int b = t; b < NBKT; b += 256) runbase[b] = atomicAdd(&gnext[b], hist[b]);
    __syncthreads();

    #pragma unroll
    for (int c = 0; c < 4; ++c) {
        #pragma unroll
        for (int j = 0; j < 4; ++j) {
            int idx = c * 4 + j;
            if (myc[idx] >= 0) {
                int e = e0 + c * 1024 + t * 4 + j;
                int b = myc[idx] >> 6;
                int cl = myc[idx] & 63;
                stage[scp[b] + myr[idx]] = (cl << 24) | e;
            }
        }
    }
    __syncthreads();

    for (int slot = t; slot < nvalid; slot += 256) {
        int lo = 0, hi = NBKT - 1;
        while (lo < hi) {
            int mid = (lo + hi + 1) >> 1;
            if (scp[mid] <= slot) lo = mid; else hi = mid - 1;
        }
        int b = lo;
        int idx = runbase[b] + (slot - scp[b]);
        if (idx < BCAP) pairs[b * BCAP + idx] = stage[slot];
    }
}

// edge MLP via MFMA: 4 waves/block, 64 edges/wave, wave-private LDS tiles.
// Tile math: mfma_f32_16x16x32_f16, A = 16 edges x K, B = weight fragments.
#define ROWP 40   // f16 row stride (80B: 16B-aligned b128, <=2-way banks)
__global__ __launch_bounds__(256) void edge_mlp_mfma_kernel(
    const float* __restrict__ x, const int* __restrict__ ei,
    const float* __restrict__ ea,
    const _Float16* __restrict__ w1f, const float* __restrict__ b1,
    const _Float16* __restrict__ w2f, const float* __restrict__ b2,
    __half* __restrict__ msg)
{
    __shared__ _Float16 lds[4][64 * ROWP + 16 * ROWP + 16 * ROWP];
    int t = threadIdx.x;
    int w = t >> 6, lane = t & 63;
    _Float16* inA = &lds[w][0];                 // [64][ROWP]
    _Float16* hT  = &lds[w][64 * ROWP];         // [16][ROWP]
    _Float16* oT  = &lds[w][80 * ROWP];         // [16][ROWP]

    int ebase = blockIdx.x * 256 + w * 64;      // grid*256 == NE exactly
    int e = ebase + lane;

    // B fragments (per-lane 16B loads from pre-packed tables)
    f16x8 wf10 = *(const f16x8*)(w1f + lane * 8);
    f16x8 wf11 = *(const f16x8*)(w1f + 512 + lane * 8);
    f16x8 wf20 = *(const f16x8*)(w2f + lane * 8);
    f16x8 wf21 = *(const f16x8*)(w2f + 512 + lane * 8);
    float b1v0 = b1[lane & 15], b1v1 = b1[16 + (lane & 15)];
    float b2v0 = b2[lane & 15], b2v1 = b2[16 + (lane & 15)];

    // stage this lane's edge input as a zero-padded f16 row of 32
    int row = ei[e];
    float in[FN + FE];
    #pragma unroll
    for (int k = 0; k < FN; ++k) in[k] = x[row * FN + k];
    const float2* ep = (const float2*)&ea[(size_t)e * FE];
    #pragma unroll
    for (int k = 0; k < FE / 2; ++k) {
        float2 v = ep[k];
        in[FN + 2*k] = v.x; in[FN + 2*k + 1] = v.y;
    }
    _Float16 inh[16];
    #pragma unroll
    for (int k = 0; k < FN + FE; ++k) inh[k] = (_Float16)in[k];
    #pragma unroll
    for (int k = FN + FE; k < 16; ++k) inh[k] = (_Float16)0.f;
    f16x8 zero8 = (f16x8)0;
    *(f16x8*)(inA + lane * ROWP + 0)  = *(f16x8*)&inh[0];
    *(f16x8*)(inA + lane * ROWP + 8)  = *(f16x8*)&inh[8];
    *(f16x8*)(inA + lane * ROWP + 16) = zero8;
    *(f16x8*)(inA + lane * ROWP + 24) = zero8;
    __syncthreads();

    int col = lane & 15;
    int rbase = (lane >> 4) * 4;

    #pragma unroll
    for (int t4 = 0; t4 < 4; ++t4) {
        // A fragment: lane holds edge=(lane&15), k=(lane>>4)*8..+7
        f16x8 a1 = *(const f16x8*)(inA + (t4 * 16 + (lane & 15)) * ROWP + (lane >> 4) * 8);
        f32x4 c0 = {b1v0, b1v0, b1v0, b1v0};
        f32x4 c1 = {b1v1, b1v1, b1v1, b1v1};
        c0 = __builtin_amdgcn_mfma_f32_16x16x32_f16(a1, wf10, c0, 0, 0, 0);
        c1 = __builtin_amdgcn_mfma_f32_16x16x32_f16(a1, wf11, c1, 0, 0, 0);
        // leaky + transpose through LDS: C layout col=lane&15,row=(lane>>4)*4+r
        #pragma unroll
        for (int r = 0; r < 4; ++r) {
            hT[(rbase + r) * ROWP + col]      = (_Float16)fmaxf(c0[r], 0.01f * c0[r]);
            hT[(rbase + r) * ROWP + 16 + col] = (_Float16)fmaxf(c1[r], 0.01f * c1[r]);
        }
        __syncthreads();
        f16x8 a2 = *(const f16x8*)(hT + (lane & 15) * ROWP + (lane >> 4) * 8);
        f32x4 d0 = {b2v0, b2v0, b2v0, b2v0};
        f32x4 d1 = {b2v1, b2v1, b2v1, b2v1};
        d0 = __builtin_amdgcn_mfma_f32_16x16x32_f16(a2, wf20, d0, 0, 0, 0);
        d1 = __builtin_amdgcn_mfma_f32_16x16x32_f16(a2, wf21, d1, 0, 0, 0);
        #pragma unroll
        for (int r = 0; r < 4; ++r) {
            oT[(rbase + r) * ROWP + col]      = (_Float16)d0[r];
            oT[(rbase + r) * ROWP + 16 + col] = (_Float16)d1[r];
        }
        __syncthreads();
        // coalesced copy-out: 16 rows x 64B
        int orow = lane >> 2, ochk = lane & 3;
        uint4 vv = *(const uint4*)(oT + orow * ROWP + ochk * 8);
        *(uint4*)(msg + (size_t)(ebase + t4 * 16 + orow) * HID + ochk * 8) = vv;
        __syncthreads();
    }
}

// P2+mean fused over 64-node buckets (unchanged from r16)
__global__ __launch_bounds__(256) void p2_mean_kernel(
    const int* __restrict__ pairs, const int* __restrict__ gnext,
    const __half* __restrict__ msg, float* __restrict__ summed)
{
    __shared__ int ncnt[64];
    __shared__ int nstart[64];
    __shared__ int cur[64];
    __shared__ int pstage[BCAP];

    int t = threadIdx.x;
    int b = blockIdx.x;
    int m = gnext[b]; if (m > BCAP) m = BCAP;
    const int* pb = pairs + b * BCAP;

    if (t < 64) ncnt[t] = 0;
    __syncthreads();
    for (int i = t; i < m; i += 256) {
        atomicAdd(&ncnt[(unsigned)pb[i] >> 24], 1);
    }
    __syncthreads();

    if (t < 64) nstart[t] = ncnt[t];
    __syncthreads();
    for (int d = 1; d < 64; d <<= 1) {
        int v = 0;
        if (t < 64) { v = nstart[t]; if (t >= d) v += nstart[t - d]; }
        __syncthreads();
        if (t < 64) nstart[t] = v;
        __syncthreads();
    }
    if (t < 64) {
        int ex = nstart[t] - ncnt[t];
        nstart[t] = ex;
        cur[t] = ex;
    }
    __syncthreads();

    for (int i = t; i < m; i += 256) {
        unsigned p = (unsigned)pb[i];
        int r = atomicAdd(&cur[p >> 24], 1);
        pstage[r] = (int)(p & 0xFFFFFFu);
    }
    __syncthreads();

    {
        int nl   = t >> 2;
        int lane = t & 3;
        int d = ncnt[nl];
        int s = nstart[nl];
        float4 alo = make_float4(0.f, 0.f, 0.f, 0.f);
        float4 ahi = make_float4(0.f, 0.f, 0.f, 0.f);
        #pragma unroll 4
        for (int i = 0; i < d; ++i) {
            int e = pstage[s + i];
            uint4 v = *(const uint4*)(msg + (size_t)e * HID + lane * 8);
            float2 f0 = __half22float2(*(__half2*)&v.x);
            float2 f1 = __half22float2(*(__half2*)&v.y);
            float2 f2 = __half22float2(*(__half2*)&v.z);
            float2 f3 = __half22float2(*(__half2*)&v.w);
            alo.x += f0.x; alo.y += f0.y; alo.z += f1.x; alo.w += f1.y;
            ahi.x += f2.x; ahi.y += f2.y; ahi.z += f3.x; ahi.w += f3.y;
        }
        int node = b * 64 + nl;
        if (node < NN) {
            float inv = 1.f / fmaxf((float)d, 1.f);
            alo.x *= inv; alo.y *= inv; alo.z *= inv; alo.w *= inv;
            ahi.x *= inv; ahi.y *= inv; ahi.z *= inv; ahi.w *= inv;
            float4* op = (float4*)&summed[(size_t)node * HID];
            op[lane * 2]     = alo;
            op[lane * 2 + 1] = ahi;
        }
    }
}

// ======================= fallback path (round-5, CSR) =====================

__global__ __launch_bounds__(256) void hist_kernel(const int* __restrict__ ei,
                                                   int* __restrict__ cnt)
{
    int e = blockIdx.x * 256 + threadIdx.x;
    if (e >= NE) return;
    atomicAdd(&cnt[ei[NE + e]], 1);
}

__global__ __launch_bounds__(1024) void scanA_kernel(const int* __restrict__ cnt,
                                                     int* __restrict__ off,
                                                     int* __restrict__ bsum)
{
    __shared__ int s[1024];
    int t = threadIdx.x;
    int i = blockIdx.x * 1024 + t;
    int v = (i < NN) ? cnt[i] : 0;
    s[t] = v;
    __syncthreads();
    for (int d = 1; d < 1024; d <<= 1) {
        int a = (t >= d) ? s[t - d] : 0;
        __syncthreads();
        s[t] += a;
        __syncthreads();
    }
    if (i < NN) off[i] = s[t] - v;
    if (t == 1023) bsum[blockIdx.x] = s[1023];
}

__global__ void scanB_kernel(int* __restrict__ bsum, int* __restrict__ boff)
{
    if (threadIdx.x == 0 && blockIdx.x == 0) {
        int run = 0;
        for (int b = 0; b < NB; ++b) { boff[b] = run; run += bsum[b]; }
    }
}

__global__ __launch_bounds__(256) void scanC_kernel(int* __restrict__ off,
                                                    const int* __restrict__ boff,
                                                    int* __restrict__ next)
{
    int i = blockIdx.x * 256 + threadIdx.x;
    if (i >= NN) return;
    int o = off[i] + boff[i >> 10];
    off[i] = o;
    next[i] = o;
}

__global__ __launch_bounds__(256) void edge_mlp_scatter_kernel(
    const float* __restrict__ x, const int* __restrict__ ei,
    const float* __restrict__ ea,
    const float* __restrict__ W1, const float* __restrict__ b1,
    const float* __restrict__ W2, const float* __restrict__ b2,
    int* __restrict__ next, __half* __restrict__ msg)
{
    int e = blockIdx.x * 256 + threadIdx.x;
    if (e >= NE) return;
    int row = ei[e];
    int col = ei[NE + e];
    int pos = atomicAdd(&next[col], 1);

    float in[FN + FE];
    #pragma unroll
    for (int k = 0; k < FN; ++k) in[k] = x[row * FN + k];
    const float2* ep = (const float2*)&ea[(size_t)e * FE];
    #pragma unroll
    for (int k = 0; k < FE / 2; ++k) {
        float2 v = ep[k];
        in[FN + 2*k] = v.x; in[FN + 2*k + 1] = v.y;
    }

    float h[HID];
    #pragma unroll
    for (int j = 0; j < HID; ++j) {
        float a = b1[j];
        #pragma unroll
        for (int k = 0; k < FN + FE; ++k) a = fmaf(in[k], W1[k * HID + j], a);
        h[j] = leaky(a);
    }
    float o[HID];
    #pragma unroll
    for (int j = 0; j < HID; ++j) {
        float a = b2[j];
        #pragma unroll
        for (int k = 0; k < HID; ++k) a = fmaf(h[k], W2[k * HID + j], a);
        o[j] = a;
    }

    __half2 hh[HID / 2];
    #pragma unroll
    for (int q = 0; q < HID / 2; ++q) hh[q] = __floats2half2_rn(o[2*q], o[2*q+1]);
    uint4* dst = (uint4*)(msg + (size_t)pos * HID);
    const uint4* src = (const uint4*)hh;
    #pragma unroll
    for (int q = 0; q < 4; ++q) dst[q] = src[q];
}

__global__ __launch_bounds__(256) void mean_csr_kernel(
    const __half* __restrict__ msg, const int* __restrict__ off,
    const int* __restrict__ cnt, float* __restrict__ summed)
{
    int gid = blockIdx.x * 256 + threadIdx.x;
    int node = gid >> 3;
    int lane = gid & 7;
    if (node >= NN) return;
    int t0 = off[node], d = cnt[node];

    float4 acc = make_float4(0.f, 0.f, 0.f, 0.f);
    const __half2* p = (const __half2*)(msg + (size_t)t0 * HID + lane * 4);
    for (int t = 0; t < d; ++t) {
        __half2 a = p[0], b = p[1];
        float2 fa = __half22float2(a), fb = __half22float2(b);
        acc.x += fa.x; acc.y += fa.y; acc.z += fb.x; acc.w += fb.y;
        p += HID / 2;
    }
    float inv = 1.f / fmaxf((float)d, 1.f);
    acc.x *= inv; acc.y *= inv; acc.z *= inv; acc.w *= inv;
    ((float4*)&summed[(size_t)node * HID])[lane] = acc;
}

// ======================= node MLP (shared) ================================

__global__ __launch_bounds__(256) void node_kernel(
    const float* __restrict__ x, const float* __restrict__ summed,
    const float* __restrict__ u,
    const int* __restrict__ batch,
    const float* __restrict__ W3, const float* __restrict__ b3,
    const float* __restrict__ W4, const float* __restrict__ b4,
    float* __restrict__ out)
{
    __shared__ __align__(16) float sW3[(FN + HID + FG) * HID];
    __shared__ __align__(16) float sW4[HID * FN];
    __shared__ __align__(16) float sb3[HID];
    __shared__ float sb4[FN];
    int tid = threadIdx.x;
    for (int i = tid; i < (FN + HID + FG) * HID; i += 256) sW3[i] = W3[i];
    for (int i = tid; i < HID * FN; i += 256) sW4[i] = W4[i];
    if (tid < HID) sb3[tid] = b3[tid];
    if (tid < FN) sb4[tid] = b4[tid];
    __syncthreads();

    int i = blockIdx.x * 256 + tid;
    if (i >= NN) return;

    float g[HID];
    #pragma unroll
    for (int jq = 0; jq < HID / 4; ++jq) {
        float4 bb = ((const float4*)sb3)[jq];
        g[4*jq+0] = bb.x; g[4*jq+1] = bb.y; g[4*jq+2] = bb.z; g[4*jq+3] = bb.w;
    }

    #pragma unroll
    for (int k = 0; k < FN; ++k) {
        float a = x[i * FN + k];
        const float4* wr = (const float4*)(sW3 + k * HID);
        #pragma unroll
        for (int jq = 0; jq < HID / 4; ++jq) {
            float4 w = wr[jq];
            g[4*jq+0] = fmaf(a, w.x, g[4*jq+0]);
            g[4*jq+1] = fmaf(a, w.y, g[4*jq+1]);
            g[4*jq+2] = fmaf(a, w.z, g[4*jq+2]);
            g[4*jq+3] = fmaf(a, w.w, g[4*jq+3]);
        }
    }

    const float4* sp = (const float4*)&summed[(size_t)i * HID];
    #pragma unroll
    for (int kq = 0; kq < HID / 4; ++kq) {
        float4 mvv = sp[kq];
        #pragma unroll
        for (int c = 0; c < 4; ++c) {
            float a = (c == 0) ? mvv.x : (c == 1) ? mvv.y : (c == 2) ? mvv.z : mvv.w;
            const float4* wr = (const float4*)(sW3 + (FN + 4*kq + c) * HID);
            #pragma unroll
            for (int jq = 0; jq < HID / 4; ++jq) {
                float4 w = wr[jq];
                g[4*jq+0] = fmaf(a, w.x, g[4*jq+0]);
                g[4*jq+1] = fmaf(a, w.y, g[4*jq+1]);
                g[4*jq+2] = fmaf(a, w.z, g[4*jq+2]);
                g[4*jq+3] = fmaf(a, w.w, g[4*jq+3]);
            }
        }
    }

    int b = batch[i];
    const float4* up = (const float4*)&u[(size_t)b * FG];
    #pragma unroll
    for (int kq = 0; kq < FG / 4; ++kq) {
        float4 uvv = up[kq];
        #pragma unroll
        for (int c = 0; c < 4; ++c) {
            float a = (c == 0) ? uvv.x : (c == 1) ? uvv.y : (c == 2) ? uvv.z : uvv.w;
            const float4* wr = (const float4*)(sW3 + (FN + HID + 4*kq + c) * HID);
            #pragma unroll
            for (int jq = 0; jq < HID / 4; ++jq) {
                float4 w = wr[jq];
                g[4*jq+0] = fmaf(a, w.x, g[4*jq+0]);
                g[4*jq+1] = fmaf(a, w.y, g[4*jq+1]);
                g[4*jq+2] = fmaf(a, w.z, g[4*jq+2]);
                g[4*jq+3] = fmaf(a, w.w, g[4*jq+3]);
            }
        }
    }

    #pragma unroll
    for (int j = 0; j < HID; ++j) g[j] = leaky(g[j]);

    #pragma unroll
    for (int j = 0; j < FN; ++j) {
        float acc = sb4[j];
        #pragma unroll
        for (int k = 0; k < HID; ++k) acc = fmaf(g[k], sW4[k * FN + j], acc);
        out[i * FN + j] = acc;
    }
}

// ======================= launch ===========================================

extern "C" void kernel_launch(void* const* d_in, const int* in_sizes, int n_in,
                              void* d_out, int out_size, void* d_ws, size_t ws_size,
                              hipStream_t stream)
{
    const float* x   = (const float*)d_in[0];
    const int*   ei  = (const int*)  d_in[1];
    const float* ea  = (const float*)d_in[2];
    const float* u   = (const float*)d_in[3];
    const int*   bat = (const int*)  d_in[4];
    const float* W1  = (const float*)d_in[5];
    const float* b1  = (const float*)d_in[6];
    const float* W2  = (const float*)d_in[7];
    const float* b2  = (const float*)d_in[8];
    const float* W3  = (const float*)d_in[9];
    const float* b3  = (const float*)d_in[10];
    const float* W4  = (const float*)d_in[11];
    const float* b4  = (const float*)d_in[12];
    float* out = (float*)d_out;

    // primary layout: gnext[1600] | w1f[1024 f16] | w2f[1024 f16] |
    //                 pairs[NBKT*BCAP] | summed[NN*HID f32] | msg[NE*HID f16]
    int*      gnext  = (int*)d_ws;
    _Float16* w1f    = (_Float16*)(gnext + 1600);
    _Float16* w2f    = w1f + 1024;
    int*      pairs  = (int*)(w2f + 1024);
    float*    summed = (float*)(pairs + (size_t)NBKT * BCAP);
    __half*   msg    = (__half*)(summed + (size_t)NN * HID);
    size_t    need   = (size_t)((char*)(msg + (size_t)NE * HID) - (char*)d_ws);

    if (ws_size >= need) {
        hipMemsetAsync(gnext, 0, 1600 * sizeof(int), stream);
        wprep_kernel<<<1, 256, 0, stream>>>(W1, W2, w1f, w2f);
        p1_partition_kernel<<<NBLK1, 256, 0, stream>>>(ei, gnext, pairs);
        edge_mlp_mfma_kernel<<<NE / 256, 256, 0, stream>>>(
            x, ei, ea, w1f, b1, w2f, b2, msg);
        p2_mean_kernel<<<NBKT, 256, 0, stream>>>(pairs, gnext, msg, summed);
        node_kernel<<<(NN + 255) / 256, 256, 0, stream>>>(
            x, summed, u, bat, W3, b3, W4, b4, out);
        return;
    }

    // fallback layout (round-5): cnt|off|next|bsum|boff|summed|msg
    int*    fcnt    = (int*)d_ws;
    int*    foff    = fcnt + NN;
    int*    fnext   = foff + NN;
    int*    fbsum   = fnext + NN;
    int*    fboff   = fbsum + NB;
    float*  fsummed = (float*)(fboff + NB);
    __half* fmsg    = (__half*)(fsummed + (size_t)NN * HID);

    hipMemsetAsync(fcnt, 0, (size_t)NN * sizeof(int), stream);
    hist_kernel<<<(NE + 255) / 256, 256, 0, stream>>>(ei, fcnt);
    scanA_kernel<<<NB, 1024, 0, stream>>>(fcnt, foff, fbsum);
    scanB_kernel<<<1, 64, 0, stream>>>(fbsum, fboff);
    scanC_kernel<<<(NN + 255) / 256, 256, 0, stream>>>(foff, fboff, fnext);
    edge_mlp_scatter_kernel<<<(NE + 255) / 256, 256, 0, stream>>>(
        x, ei, ea, W1, b1, W2, b2, fnext, fmsg);
    mean_csr_kernel<<<(NN * 8 + 255) / 256, 256, 0, stream>>>(fmsg, foff, fcnt, fsummed);
    node_kernel<<<(NN + 255) / 256, 256, 0, stream>>>(
        x, fsummed, u, bat, W3, b3, W4, b4, out);
}

// Round 18
// 237.051 us; speedup vs baseline: 1.8492x; 1.0337x over previous
//
#include <hip/hip_runtime.h>
#include <hip/hip_fp16.h>

#define NN 100000
#define NE 3200000
#define FN 7
#define FE 6
#define FG 64
#define HID 32
#define EPB 4096                          // edges per P1 block
#define NBLK1 ((NE + EPB - 1) / EPB)      // 782
#define NEBLK (NE / 256)                  // 12500 edge-MFMA blocks
#define NBKT ((NN + 63) >> 6)             // 1563 coarse buckets (64 nodes each)
#define BCAP 2432                         // per-bucket cap (mean 2048 + 8.5 sigma)
#define NB ((NN + 1023) / 1024)           // fallback scan blocks
#define ROWP 40                           // f16 row stride (80B)

typedef int i32x4 __attribute__((ext_vector_type(4)));
typedef _Float16 f16x8 __attribute__((ext_vector_type(8)));
typedef float f32x4 __attribute__((ext_vector_type(4)));

__device__ __forceinline__ float leaky(float v) { return v >= 0.f ? v : 0.01f * v; }

// ======================= weight prep: MFMA B-fragments ====================
__global__ __launch_bounds__(256) void wprep_kernel(
    const float* __restrict__ W1, const float* __restrict__ W2,
    _Float16* __restrict__ w1f, _Float16* __restrict__ w2f)
{
    int t = threadIdx.x;
    for (int idx = t; idx < 1024; idx += 256) {
        int f = idx >> 9, rem = idx & 511, l = rem >> 3, i = rem & 7;
        int k = (l >> 4) * 8 + i, col = f * 16 + (l & 15);
        w1f[idx] = (k < FN + FE) ? (_Float16)W1[k * HID + col] : (_Float16)0.f;
        w2f[idx] = (_Float16)W2[k * HID + col];
    }
}

// ======================= merged P1 ∪ edge-MFMA kernel =====================
// blocks [0,NBLK1): coarse partition (LDS 30.8KB, runbase overlaid on hist)
// blocks [NBLK1, NBLK1+NEBLK): MFMA edge MLP (LDS 30.7KB)

__global__ __launch_bounds__(256) void p1_edge_kernel(
    const float* __restrict__ x, const int* __restrict__ ei,
    const float* __restrict__ ea,
    const _Float16* __restrict__ w1f, const float* __restrict__ b1,
    const _Float16* __restrict__ w2f, const float* __restrict__ b2,
    int* __restrict__ gnext, int* __restrict__ pairs,
    __half* __restrict__ msg)
{
    __shared__ __align__(16) char smem[30848];   // union of both branches
    int t = threadIdx.x;

    if (blockIdx.x >= NBLK1) {
        // ---------------- edge-MFMA branch ----------------
        int w = t >> 6, lane = t & 63;
        _Float16* wb = (_Float16*)smem + w * (96 * ROWP);
        _Float16* inA = wb;                     // [64][ROWP]
        _Float16* hT  = wb + 64 * ROWP;         // [16][ROWP]
        _Float16* oT  = wb + 80 * ROWP;         // [16][ROWP]

        int ebase = (blockIdx.x - NBLK1) * 256 + w * 64;
        int e = ebase + lane;

        f16x8 wf10 = *(const f16x8*)(w1f + lane * 8);
        f16x8 wf11 = *(const f16x8*)(w1f + 512 + lane * 8);
        f16x8 wf20 = *(const f16x8*)(w2f + lane * 8);
        f16x8 wf21 = *(const f16x8*)(w2f + 512 + lane * 8);
        float b1v0 = b1[lane & 15], b1v1 = b1[16 + (lane & 15)];
        float b2v0 = b2[lane & 15], b2v1 = b2[16 + (lane & 15)];

        int row = ei[e];
        float in[FN + FE];
        #pragma unroll
        for (int k = 0; k < FN; ++k) in[k] = x[row * FN + k];
        const float2* ep = (const float2*)&ea[(size_t)e * FE];
        #pragma unroll
        for (int k = 0; k < FE / 2; ++k) {
            float2 v = ep[k];
            in[FN + 2*k] = v.x; in[FN + 2*k + 1] = v.y;
        }
        _Float16 inh[16];
        #pragma unroll
        for (int k = 0; k < FN + FE; ++k) inh[k] = (_Float16)in[k];
        #pragma unroll
        for (int k = FN + FE; k < 16; ++k) inh[k] = (_Float16)0.f;
        f16x8 zero8 = (f16x8)0;
        *(f16x8*)(inA + lane * ROWP + 0)  = *(f16x8*)&inh[0];
        *(f16x8*)(inA + lane * ROWP + 8)  = *(f16x8*)&inh[8];
        *(f16x8*)(inA + lane * ROWP + 16) = zero8;
        *(f16x8*)(inA + lane * ROWP + 24) = zero8;
        __syncthreads();

        int col = lane & 15;
        int rbase = (lane >> 4) * 4;

        #pragma unroll
        for (int t4 = 0; t4 < 4; ++t4) {
            f16x8 a1 = *(const f16x8*)(inA + (t4 * 16 + (lane & 15)) * ROWP + (lane >> 4) * 8);
            f32x4 c0 = {b1v0, b1v0, b1v0, b1v0};
            f32x4 c1 = {b1v1, b1v1, b1v1, b1v1};
            c0 = __builtin_amdgcn_mfma_f32_16x16x32_f16(a1, wf10, c0, 0, 0, 0);
            c1 = __builtin_amdgcn_mfma_f32_16x16x32_f16(a1, wf11, c1, 0, 0, 0);
            #pragma unroll
            for (int r = 0; r < 4; ++r) {
                hT[(rbase + r) * ROWP + col]      = (_Float16)fmaxf(c0[r], 0.01f * c0[r]);
                hT[(rbase + r) * ROWP + 16 + col] = (_Float16)fmaxf(c1[r], 0.01f * c1[r]);
            }
            __syncthreads();
            f16x8 a2 = *(const f16x8*)(hT + (lane & 15) * ROWP + (lane >> 4) * 8);
            f32x4 d0 = {b2v0, b2v0, b2v0, b2v0};
            f32x4 d1 = {b2v1, b2v1, b2v1, b2v1};
            d0 = __builtin_amdgcn_mfma_f32_16x16x32_f16(a2, wf20, d0, 0, 0, 0);
            d1 = __builtin_amdgcn_mfma_f32_16x16x32_f16(a2, wf21, d1, 0, 0, 0);
            #pragma unroll
            for (int r = 0; r < 4; ++r) {
                oT[(rbase + r) * ROWP + col]      = (_Float16)d0[r];
                oT[(rbase + r) * ROWP + 16 + col] = (_Float16)d1[r];
            }
            __syncthreads();
            int orow = lane >> 2, ochk = lane & 3;
            uint4 vv = *(const uint4*)(oT + orow * ROWP + ochk * 8);
            *(uint4*)(msg + (size_t)(ebase + t4 * 16 + orow) * HID + ochk * 8) = vv;
            __syncthreads();
        }
        return;
    }

    // ---------------- P1 branch: coarse partition ----------------
    int* hist  = (int*)smem;          // [NBKT]; becomes runbase after overlay
    int* scp   = hist + NBKT;         // [2048]
    int* stage = scp + 2048;          // [EPB]

    int e0 = blockIdx.x * EPB;
    int nvalid = NE - e0; if (nvalid > EPB) nvalid = EPB;

    for (int i = t; i < NBKT; i += 256) hist[i] = 0;
    __syncthreads();

    int myc[16];
    int myr[16];
    #pragma unroll
    for (int c = 0; c < 4; ++c) {
        int base = e0 + c * 1024 + t * 4;
        if (base + 3 < NE) {
            i32x4 cols = *(const i32x4*)&ei[NE + base];
            #pragma unroll
            for (int j = 0; j < 4; ++j) {
                int col = cols[j];
                myc[c * 4 + j] = col;
                myr[c * 4 + j] = atomicAdd(&hist[col >> 6], 1);
            }
        } else {
            #pragma unroll
            for (int j = 0; j < 4; ++j) {
                int e = base + j;
                myc[c * 4 + j] = -1;
                if (e < NE) {
                    int col = ei[NE + e];
                    myc[c * 4 + j] = col;
                    myr[c * 4 + j] = atomicAdd(&hist[col >> 6], 1);
                }
            }
        }
    }
    __syncthreads();

    #pragma unroll
    for (int s = 0; s < 8; ++s) {
        int idx = t + s * 256;
        scp[idx] = (idx < NBKT) ? hist[idx] : 0;
    }
    __syncthreads();
    for (int d = 1; d < 2048; d <<= 1) {
        int v[8];
        #pragma unroll
        for (int s = 0; s < 8; ++s) {
            int idx = t + s * 256;
            v[s] = scp[idx];
            if (idx >= d) v[s] += scp[idx - d];
        }
        __syncthreads();
        #pragma unroll
        for (int s = 0; s < 8; ++s) scp[t + s * 256] = v[s];
        __syncthreads();
    }
    {
        int v[8];
        #pragma unroll
        for (int s = 0; s < 8; ++s) {
            int idx = t + s * 256;
            v[s] = scp[idx] - ((idx < NBKT) ? hist[idx] : 0);
        }
        __syncthreads();
        #pragma unroll
        for (int s = 0; s < 8; ++s) scp[t + s * 256] = v[s];
        __syncthreads();
    }
    // reserve global runs; overlay runbase onto hist
    for (int b = t; b < NBKT; b += 256) {
        int rb = atomicAdd(&gnext[b], hist[b]);
        hist[b] = rb;
    }
    __syncthreads();

    #pragma unroll
    for (int c = 0; c < 4; ++c) {
        #pragma unroll
        for (int j = 0; j < 4; ++j) {
            int idx = c * 4 + j;
            if (myc[idx] >= 0) {
                int e = e0 + c * 1024 + t * 4 + j;
                int b = myc[idx] >> 6;
                int cl = myc[idx] & 63;
                stage[scp[b] + myr[idx]] = (cl << 24) | e;
            }
        }
    }
    __syncthreads();

    for (int slot = t; slot < nvalid; slot += 256) {
        int lo = 0, hi = NBKT - 1;
        while (lo < hi) {
            int mid = (lo + hi + 1) >> 1;
            if (scp[mid] <= slot) lo = mid; else hi = mid - 1;
        }
        int b = lo;
        int idx = hist[b] + (slot - scp[b]);   // hist[b] == runbase
        if (idx < BCAP) pairs[b * BCAP + idx] = stage[slot];
    }
}

// P2+mean fused over 64-node buckets (unchanged from r16/r17)
__global__ __launch_bounds__(256) void p2_mean_kernel(
    const int* __restrict__ pairs, const int* __restrict__ gnext,
    const __half* __restrict__ msg, float* __restrict__ summed)
{
    __shared__ int ncnt[64];
    __shared__ int nstart[64];
    __shared__ int cur[64];
    __shared__ int pstage[BCAP];

    int t = threadIdx.x;
    int b = blockIdx.x;
    int m = gnext[b]; if (m > BCAP) m = BCAP;
    const int* pb = pairs + b * BCAP;

    if (t < 64) ncnt[t] = 0;
    __syncthreads();
    for (int i = t; i < m; i += 256) {
        atomicAdd(&ncnt[(unsigned)pb[i] >> 24], 1);
    }
    __syncthreads();

    if (t < 64) nstart[t] = ncnt[t];
    __syncthreads();
    for (int d = 1; d < 64; d <<= 1) {
        int v = 0;
        if (t < 64) { v = nstart[t]; if (t >= d) v += nstart[t - d]; }
        __syncthreads();
        if (t < 64) nstart[t] = v;
        __syncthreads();
    }
    if (t < 64) {
        int ex = nstart[t] - ncnt[t];
        nstart[t] = ex;
        cur[t] = ex;
    }
    __syncthreads();

    for (int i = t; i < m; i += 256) {
        unsigned p = (unsigned)pb[i];
        int r = atomicAdd(&cur[p >> 24], 1);
        pstage[r] = (int)(p & 0xFFFFFFu);
    }
    __syncthreads();

    {
        int nl   = t >> 2;
        int lane = t & 3;
        int d = ncnt[nl];
        int s = nstart[nl];
        float4 alo = make_float4(0.f, 0.f, 0.f, 0.f);
        float4 ahi = make_float4(0.f, 0.f, 0.f, 0.f);
        #pragma unroll 4
        for (int i = 0; i < d; ++i) {
            int e = pstage[s + i];
            uint4 v = *(const uint4*)(msg + (size_t)e * HID + lane * 8);
            float2 f0 = __half22float2(*(__half2*)&v.x);
            float2 f1 = __half22float2(*(__half2*)&v.y);
            float2 f2 = __half22float2(*(__half2*)&v.z);
            float2 f3 = __half22float2(*(__half2*)&v.w);
            alo.x += f0.x; alo.y += f0.y; alo.z += f1.x; alo.w += f1.y;
            ahi.x += f2.x; ahi.y += f2.y; ahi.z += f3.x; ahi.w += f3.y;
        }
        int node = b * 64 + nl;
        if (node < NN) {
            float inv = 1.f / fmaxf((float)d, 1.f);
            alo.x *= inv; alo.y *= inv; alo.z *= inv; alo.w *= inv;
            ahi.x *= inv; ahi.y *= inv; ahi.z *= inv; ahi.w *= inv;
            float4* op = (float4*)&summed[(size_t)node * HID];
            op[lane * 2]     = alo;
            op[lane * 2 + 1] = ahi;
        }
    }
}

// ======================= fallback path (round-5, CSR) =====================

__global__ __launch_bounds__(256) void hist_kernel(const int* __restrict__ ei,
                                                   int* __restrict__ cnt)
{
    int e = blockIdx.x * 256 + threadIdx.x;
    if (e >= NE) return;
    atomicAdd(&cnt[ei[NE + e]], 1);
}

__global__ __launch_bounds__(1024) void scanA_kernel(const int* __restrict__ cnt,
                                                     int* __restrict__ off,
                                                     int* __restrict__ bsum)
{
    __shared__ int s[1024];
    int t = threadIdx.x;
    int i = blockIdx.x * 1024 + t;
    int v = (i < NN) ? cnt[i] : 0;
    s[t] = v;
    __syncthreads();
    for (int d = 1; d < 1024; d <<= 1) {
        int a = (t >= d) ? s[t - d] : 0;
        __syncthreads();
        s[t] += a;
        __syncthreads();
    }
    if (i < NN) off[i] = s[t] - v;
    if (t == 1023) bsum[blockIdx.x] = s[1023];
}

__global__ void scanB_kernel(int* __restrict__ bsum, int* __restrict__ boff)
{
    if (threadIdx.x == 0 && blockIdx.x == 0) {
        int run = 0;
        for (int b = 0; b < NB; ++b) { boff[b] = run; run += bsum[b]; }
    }
}

__global__ __launch_bounds__(256) void scanC_kernel(int* __restrict__ off,
                                                    const int* __restrict__ boff,
                                                    int* __restrict__ next)
{
    int i = blockIdx.x * 256 + threadIdx.x;
    if (i >= NN) return;
    int o = off[i] + boff[i >> 10];
    off[i] = o;
    next[i] = o;
}

__global__ __launch_bounds__(256) void edge_mlp_scatter_kernel(
    const float* __restrict__ x, const int* __restrict__ ei,
    const float* __restrict__ ea,
    const float* __restrict__ W1, const float* __restrict__ b1,
    const float* __restrict__ W2, const float* __restrict__ b2,
    int* __restrict__ next, __half* __restrict__ msg)
{
    int e = blockIdx.x * 256 + threadIdx.x;
    if (e >= NE) return;
    int row = ei[e];
    int col = ei[NE + e];
    int pos = atomicAdd(&next[col], 1);

    float in[FN + FE];
    #pragma unroll
    for (int k = 0; k < FN; ++k) in[k] = x[row * FN + k];
    const float2* ep = (const float2*)&ea[(size_t)e * FE];
    #pragma unroll
    for (int k = 0; k < FE / 2; ++k) {
        float2 v = ep[k];
        in[FN + 2*k] = v.x; in[FN + 2*k + 1] = v.y;
    }

    float h[HID];
    #pragma unroll
    for (int j = 0; j < HID; ++j) {
        float a = b1[j];
        #pragma unroll
        for (int k = 0; k < FN + FE; ++k) a = fmaf(in[k], W1[k * HID + j], a);
        h[j] = leaky(a);
    }
    float o[HID];
    #pragma unroll
    for (int j = 0; j < HID; ++j) {
        float a = b2[j];
        #pragma unroll
        for (int k = 0; k < HID; ++k) a = fmaf(h[k], W2[k * HID + j], a);
        o[j] = a;
    }

    __half2 hh[HID / 2];
    #pragma unroll
    for (int q = 0; q < HID / 2; ++q) hh[q] = __floats2half2_rn(o[2*q], o[2*q+1]);
    uint4* dst = (uint4*)(msg + (size_t)pos * HID);
    const uint4* src = (const uint4*)hh;
    #pragma unroll
    for (int q = 0; q < 4; ++q) dst[q] = src[q];
}

__global__ __launch_bounds__(256) void mean_csr_kernel(
    const __half* __restrict__ msg, const int* __restrict__ off,
    const int* __restrict__ cnt, float* __restrict__ summed)
{
    int gid = blockIdx.x * 256 + threadIdx.x;
    int node = gid >> 3;
    int lane = gid & 7;
    if (node >= NN) return;
    int t0 = off[node], d = cnt[node];

    float4 acc = make_float4(0.f, 0.f, 0.f, 0.f);
    const __half2* p = (const __half2*)(msg + (size_t)t0 * HID + lane * 4);
    for (int t = 0; t < d; ++t) {
        __half2 a = p[0], b = p[1];
        float2 fa = __half22float2(a), fb = __half22float2(b);
        acc.x += fa.x; acc.y += fa.y; acc.z += fb.x; acc.w += fb.y;
        p += HID / 2;
    }
    float inv = 1.f / fmaxf((float)d, 1.f);
    acc.x *= inv; acc.y *= inv; acc.z *= inv; acc.w *= inv;
    ((float4*)&summed[(size_t)node * HID])[lane] = acc;
}

// ======================= node MLP (shared) ================================

__global__ __launch_bounds__(256) void node_kernel(
    const float* __restrict__ x, const float* __restrict__ summed,
    const float* __restrict__ u,
    const int* __restrict__ batch,
    const float* __restrict__ W3, const float* __restrict__ b3,
    const float* __restrict__ W4, const float* __restrict__ b4,
    float* __restrict__ out)
{
    __shared__ __align__(16) float sW3[(FN + HID + FG) * HID];
    __shared__ __align__(16) float sW4[HID * FN];
    __shared__ __align__(16) float sb3[HID];
    __shared__ float sb4[FN];
    int tid = threadIdx.x;
    for (int i = tid; i < (FN + HID + FG) * HID; i += 256) sW3[i] = W3[i];
    for (int i = tid; i < HID * FN; i += 256) sW4[i] = W4[i];
    if (tid < HID) sb3[tid] = b3[tid];
    if (tid < FN) sb4[tid] = b4[tid];
    __syncthreads();

    int i = blockIdx.x * 256 + tid;
    if (i >= NN) return;

    float g[HID];
    #pragma unroll
    for (int jq = 0; jq < HID / 4; ++jq) {
        float4 bb = ((const float4*)sb3)[jq];
        g[4*jq+0] = bb.x; g[4*jq+1] = bb.y; g[4*jq+2] = bb.z; g[4*jq+3] = bb.w;
    }

    #pragma unroll
    for (int k = 0; k < FN; ++k) {
        float a = x[i * FN + k];
        const float4* wr = (const float4*)(sW3 + k * HID);
        #pragma unroll
        for (int jq = 0; jq < HID / 4; ++jq) {
            float4 w = wr[jq];
            g[4*jq+0] = fmaf(a, w.x, g[4*jq+0]);
            g[4*jq+1] = fmaf(a, w.y, g[4*jq+1]);
            g[4*jq+2] = fmaf(a, w.z, g[4*jq+2]);
            g[4*jq+3] = fmaf(a, w.w, g[4*jq+3]);
        }
    }

    const float4* sp = (const float4*)&summed[(size_t)i * HID];
    #pragma unroll
    for (int kq = 0; kq < HID / 4; ++kq) {
        float4 mvv = sp[kq];
        #pragma unroll
        for (int c = 0; c < 4; ++c) {
            float a = (c == 0) ? mvv.x : (c == 1) ? mvv.y : (c == 2) ? mvv.z : mvv.w;
            const float4* wr = (const float4*)(sW3 + (FN + 4*kq + c) * HID);
            #pragma unroll
            for (int jq = 0; jq < HID / 4; ++jq) {
                float4 w = wr[jq];
                g[4*jq+0] = fmaf(a, w.x, g[4*jq+0]);
                g[4*jq+1] = fmaf(a, w.y, g[4*jq+1]);
                g[4*jq+2] = fmaf(a, w.z, g[4*jq+2]);
                g[4*jq+3] = fmaf(a, w.w, g[4*jq+3]);
            }
        }
    }

    int b = batch[i];
    const float4* up = (const float4*)&u[(size_t)b * FG];
    #pragma unroll
    for (int kq = 0; kq < FG / 4; ++kq) {
        float4 uvv = up[kq];
        #pragma unroll
        for (int c = 0; c < 4; ++c) {
            float a = (c == 0) ? uvv.x : (c == 1) ? uvv.y : (c == 2) ? uvv.z : uvv.w;
            const float4* wr = (const float4*)(sW3 + (FN + HID + 4*kq + c) * HID);
            #pragma unroll
            for (int jq = 0; jq < HID / 4; ++jq) {
                float4 w = wr[jq];
                g[4*jq+0] = fmaf(a, w.x, g[4*jq+0]);
                g[4*jq+1] = fmaf(a, w.y, g[4*jq+1]);
                g[4*jq+2] = fmaf(a, w.z, g[4*jq+2]);
                g[4*jq+3] = fmaf(a, w.w, g[4*jq+3]);
            }
        }
    }

    #pragma unroll
    for (int j = 0; j < HID; ++j) g[j] = leaky(g[j]);

    #pragma unroll
    for (int j = 0; j < FN; ++j) {
        float acc = sb4[j];
        #pragma unroll
        for (int k = 0; k < HID; ++k) acc = fmaf(g[k], sW4[k * FN + j], acc);
        out[i * FN + j] = acc;
    }
}

// ======================= launch ===========================================

extern "C" void kernel_launch(void* const* d_in, const int* in_sizes, int n_in,
                              void* d_out, int out_size, void* d_ws, size_t ws_size,
                              hipStream_t stream)
{
    const float* x   = (const float*)d_in[0];
    const int*   ei  = (const int*)  d_in[1];
    const float* ea  = (const float*)d_in[2];
    const float* u   = (const float*)d_in[3];
    const int*   bat = (const int*)  d_in[4];
    const float* W1  = (const float*)d_in[5];
    const float* b1  = (const float*)d_in[6];
    const float* W2  = (const float*)d_in[7];
    const float* b2  = (const float*)d_in[8];
    const float* W3  = (const float*)d_in[9];
    const float* b3  = (const float*)d_in[10];
    const float* W4  = (const float*)d_in[11];
    const float* b4  = (const float*)d_in[12];
    float* out = (float*)d_out;

    // primary layout: gnext[1600] | w1f[1024 f16] | w2f[1024 f16] |
    //                 pairs[NBKT*BCAP] | summed[NN*HID f32] | msg[NE*HID f16]
    int*      gnext  = (int*)d_ws;
    _Float16* w1f    = (_Float16*)(gnext + 1600);
    _Float16* w2f    = w1f + 1024;
    int*      pairs  = (int*)(w2f + 1024);
    float*    summed = (float*)(pairs + (size_t)NBKT * BCAP);
    __half*   msg    = (__half*)(summed + (size_t)NN * HID);
    size_t    need   = (size_t)((char*)(msg + (size_t)NE * HID) - (char*)d_ws);

    if (ws_size >= need) {
        hipMemsetAsync(gnext, 0, 1600 * sizeof(int), stream);
        wprep_kernel<<<1, 256, 0, stream>>>(W1, W2, w1f, w2f);
        p1_edge_kernel<<<NBLK1 + NEBLK, 256, 0, stream>>>(
            x, ei, ea, w1f, b1, w2f, b2, gnext, pairs, msg);
        p2_mean_kernel<<<NBKT, 256, 0, stream>>>(pairs, gnext, msg, summed);
        node_kernel<<<(NN + 255) / 256, 256, 0, stream>>>(
            x, summed, u, bat, W3, b3, W4, b4, out);
        return;
    }

    // fallback layout (round-5): cnt|off|next|bsum|boff|summed|msg
    int*    fcnt    = (int*)d_ws;
    int*    foff    = fcnt + NN;
    int*    fnext   = foff + NN;
    int*    fbsum   = fnext + NN;
    int*    fboff   = fbsum + NB;
    float*  fsummed = (float*)(fboff + NB);
    __half* fmsg    = (__half*)(fsummed + (size_t)NN * HID);

    hipMemsetAsync(fcnt, 0, (size_t)NN * sizeof(int), stream);
    hist_kernel<<<(NE + 255) / 256, 256, 0, stream>>>(ei, fcnt);
    scanA_kernel<<<NB, 1024, 0, stream>>>(fcnt, foff, fbsum);
    scanB_kernel<<<1, 64, 0, stream>>>(fbsum, fboff);
    scanC_kernel<<<(NN + 255) / 256, 256, 0, stream>>>(foff, fboff, fnext);
    edge_mlp_scatter_kernel<<<(NE + 255) / 256, 256, 0, stream>>>(
        x, ei, ea, W1, b1, W2, b2, fnext, fmsg);
    mean_csr_kernel<<<(NN * 8 + 255) / 256, 256, 0, stream>>>(fmsg, foff, fcnt, fsummed);
    node_kernel<<<(NN + 255) / 256, 256, 0, stream>>>(
        x, fsummed, u, bat, W3, b3, W4, b4, out);
}

// Round 19
// 236.281 us; speedup vs baseline: 1.8552x; 1.0033x over previous
//
#include <hip/hip_runtime.h>
#include <hip/hip_fp16.h>

#define NN 100000
#define NE 3200000
#define FN 7
#define FE 6
#define FG 64
#define HID 32
#define EPB 4096                          // edges per P1 block
#define NBLK1 ((NE + EPB - 1) / EPB)      // 782
#define NEBLK (NE / 256)                  // 12500 edge-MFMA blocks
#define NBKT ((NN + 63) >> 6)             // 1563 coarse buckets (64 nodes each)
#define BCAP 2432                         // per-bucket cap (mean 2048 + 8.5 sigma)
#define NB ((NN + 1023) / 1024)           // fallback scan blocks
#define ROWP 40                           // f16 row stride (80B)

typedef int i32x4 __attribute__((ext_vector_type(4)));
typedef _Float16 f16x8 __attribute__((ext_vector_type(8)));
typedef float f32x4 __attribute__((ext_vector_type(4)));

__device__ __forceinline__ float leaky(float v) { return v >= 0.f ? v : 0.01f * v; }

// wave-local LDS fence: all LDS tiles in the edge branch are wave-private,
// so completion of this wave's LDS ops (lgkmcnt) is the only hazard.
__device__ __forceinline__ void wave_lds_fence() {
    asm volatile("s_waitcnt lgkmcnt(0)" ::: "memory");
}

// ======================= weight prep: MFMA B-fragments ====================
__global__ __launch_bounds__(256) void wprep_kernel(
    const float* __restrict__ W1, const float* __restrict__ W2,
    _Float16* __restrict__ w1f, _Float16* __restrict__ w2f)
{
    int t = threadIdx.x;
    for (int idx = t; idx < 1024; idx += 256) {
        int f = idx >> 9, rem = idx & 511, l = rem >> 3, i = rem & 7;
        int k = (l >> 4) * 8 + i, col = f * 16 + (l & 15);
        w1f[idx] = (k < FN + FE) ? (_Float16)W1[k * HID + col] : (_Float16)0.f;
        w2f[idx] = (_Float16)W2[k * HID + col];
    }
}

// ======================= merged P1 ∪ edge-MFMA kernel =====================

__global__ __launch_bounds__(256) void p1_edge_kernel(
    const float* __restrict__ x, const int* __restrict__ ei,
    const float* __restrict__ ea,
    const _Float16* __restrict__ w1f, const float* __restrict__ b1,
    const _Float16* __restrict__ w2f, const float* __restrict__ b2,
    int* __restrict__ gnext, int* __restrict__ pairs,
    __half* __restrict__ msg)
{
    __shared__ __align__(16) char smem[30848];   // union of both branches
    int t = threadIdx.x;

    if (blockIdx.x >= NBLK1) {
        // ---------------- edge-MFMA branch (wave-private LDS) ----------------
        int w = t >> 6, lane = t & 63;
        _Float16* wb = (_Float16*)smem + w * (96 * ROWP);
        _Float16* inA = wb;                     // [64][ROWP]
        _Float16* hT  = wb + 64 * ROWP;         // [16][ROWP]
        _Float16* oT  = wb + 80 * ROWP;         // [16][ROWP]

        int ebase = (blockIdx.x - NBLK1) * 256 + w * 64;
        int e = ebase + lane;

        f16x8 wf10 = *(const f16x8*)(w1f + lane * 8);
        f16x8 wf11 = *(const f16x8*)(w1f + 512 + lane * 8);
        f16x8 wf20 = *(const f16x8*)(w2f + lane * 8);
        f16x8 wf21 = *(const f16x8*)(w2f + 512 + lane * 8);
        float b1v0 = b1[lane & 15], b1v1 = b1[16 + (lane & 15)];
        float b2v0 = b2[lane & 15], b2v1 = b2[16 + (lane & 15)];

        int row = ei[e];
        float in[FN + FE];
        #pragma unroll
        for (int k = 0; k < FN; ++k) in[k] = x[row * FN + k];
        const float2* ep = (const float2*)&ea[(size_t)e * FE];
        #pragma unroll
        for (int k = 0; k < FE / 2; ++k) {
            float2 v = ep[k];
            in[FN + 2*k] = v.x; in[FN + 2*k + 1] = v.y;
        }
        _Float16 inh[16];
        #pragma unroll
        for (int k = 0; k < FN + FE; ++k) inh[k] = (_Float16)in[k];
        #pragma unroll
        for (int k = FN + FE; k < 16; ++k) inh[k] = (_Float16)0.f;
        f16x8 zero8 = (f16x8)0;
        *(f16x8*)(inA + lane * ROWP + 0)  = *(f16x8*)&inh[0];
        *(f16x8*)(inA + lane * ROWP + 8)  = *(f16x8*)&inh[8];
        *(f16x8*)(inA + lane * ROWP + 16) = zero8;
        *(f16x8*)(inA + lane * ROWP + 24) = zero8;
        wave_lds_fence();

        int col = lane & 15;
        int rbase = (lane >> 4) * 4;

        #pragma unroll
        for (int t4 = 0; t4 < 4; ++t4) {
            f16x8 a1 = *(const f16x8*)(inA + (t4 * 16 + (lane & 15)) * ROWP + (lane >> 4) * 8);
            f32x4 c0 = {b1v0, b1v0, b1v0, b1v0};
            f32x4 c1 = {b1v1, b1v1, b1v1, b1v1};
            c0 = __builtin_amdgcn_mfma_f32_16x16x32_f16(a1, wf10, c0, 0, 0, 0);
            c1 = __builtin_amdgcn_mfma_f32_16x16x32_f16(a1, wf11, c1, 0, 0, 0);
            #pragma unroll
            for (int r = 0; r < 4; ++r) {
                hT[(rbase + r) * ROWP + col]      = (_Float16)fmaxf(c0[r], 0.01f * c0[r]);
                hT[(rbase + r) * ROWP + 16 + col] = (_Float16)fmaxf(c1[r], 0.01f * c1[r]);
            }
            wave_lds_fence();
            f16x8 a2 = *(const f16x8*)(hT + (lane & 15) * ROWP + (lane >> 4) * 8);
            f32x4 d0 = {b2v0, b2v0, b2v0, b2v0};
            f32x4 d1 = {b2v1, b2v1, b2v1, b2v1};
            d0 = __builtin_amdgcn_mfma_f32_16x16x32_f16(a2, wf20, d0, 0, 0, 0);
            d1 = __builtin_amdgcn_mfma_f32_16x16x32_f16(a2, wf21, d1, 0, 0, 0);
            #pragma unroll
            for (int r = 0; r < 4; ++r) {
                oT[(rbase + r) * ROWP + col]      = (_Float16)d0[r];
                oT[(rbase + r) * ROWP + 16 + col] = (_Float16)d1[r];
            }
            wave_lds_fence();
            int orow = lane >> 2, ochk = lane & 3;
            uint4 vv = *(const uint4*)(oT + orow * ROWP + ochk * 8);
            *(uint4*)(msg + (size_t)(ebase + t4 * 16 + orow) * HID + ochk * 8) = vv;
            wave_lds_fence();   // oT read complete before next tile overwrites
        }
        return;
    }

    // ---------------- P1 branch: coarse partition (block-wide) ----------------
    int* hist  = (int*)smem;          // [NBKT]; becomes runbase after overlay
    int* scp   = hist + NBKT;         // [2048]
    int* stage = scp + 2048;          // [EPB]

    int e0 = blockIdx.x * EPB;
    int nvalid = NE - e0; if (nvalid > EPB) nvalid = EPB;

    for (int i = t; i < NBKT; i += 256) hist[i] = 0;
    __syncthreads();

    int myc[16];
    int myr[16];
    #pragma unroll
    for (int c = 0; c < 4; ++c) {
        int base = e0 + c * 1024 + t * 4;
        if (base + 3 < NE) {
            i32x4 cols = *(const i32x4*)&ei[NE + base];
            #pragma unroll
            for (int j = 0; j < 4; ++j) {
                int col = cols[j];
                myc[c * 4 + j] = col;
                myr[c * 4 + j] = atomicAdd(&hist[col >> 6], 1);
            }
        } else {
            #pragma unroll
            for (int j = 0; j < 4; ++j) {
                int e = base + j;
                myc[c * 4 + j] = -1;
                if (e < NE) {
                    int col = ei[NE + e];
                    myc[c * 4 + j] = col;
                    myr[c * 4 + j] = atomicAdd(&hist[col >> 6], 1);
                }
            }
        }
    }
    __syncthreads();

    #pragma unroll
    for (int s = 0; s < 8; ++s) {
        int idx = t + s * 256;
        scp[idx] = (idx < NBKT) ? hist[idx] : 0;
    }
    __syncthreads();
    for (int d = 1; d < 2048; d <<= 1) {
        int v[8];
        #pragma unroll
        for (int s = 0; s < 8; ++s) {
            int idx = t + s * 256;
            v[s] = scp[idx];
            if (idx >= d) v[s] += scp[idx - d];
        }
        __syncthreads();
        #pragma unroll
        for (int s = 0; s < 8; ++s) scp[t + s * 256] = v[s];
        __syncthreads();
    }
    {
        int v[8];
        #pragma unroll
        for (int s = 0; s < 8; ++s) {
            int idx = t + s * 256;
            v[s] = scp[idx] - ((idx < NBKT) ? hist[idx] : 0);
        }
        __syncthreads();
        #pragma unroll
        for (int s = 0; s < 8; ++s) scp[t + s * 256] = v[s];
        __syncthreads();
    }
    for (int b = t; b < NBKT; b += 256) {
        int rb = atomicAdd(&gnext[b], hist[b]);
        hist[b] = rb;
    }
    __syncthreads();

    #pragma unroll
    for (int c = 0; c < 4; ++c) {
        #pragma unroll
        for (int j = 0; j < 4; ++j) {
            int idx = c * 4 + j;
            if (myc[idx] >= 0) {
                int e = e0 + c * 1024 + t * 4 + j;
                int b = myc[idx] >> 6;
                int cl = myc[idx] & 63;
                stage[scp[b] + myr[idx]] = (cl << 24) | e;
            }
        }
    }
    __syncthreads();

    for (int slot = t; slot < nvalid; slot += 256) {
        int lo = 0, hi = NBKT - 1;
        while (lo < hi) {
            int mid = (lo + hi + 1) >> 1;
            if (scp[mid] <= slot) lo = mid; else hi = mid - 1;
        }
        int b = lo;
        int idx = hist[b] + (slot - scp[b]);   // hist[b] == runbase
        if (idx < BCAP) pairs[b * BCAP + idx] = stage[slot];
    }
}

// P2+mean fused over 64-node buckets (unchanged)
__global__ __launch_bounds__(256) void p2_mean_kernel(
    const int* __restrict__ pairs, const int* __restrict__ gnext,
    const __half* __restrict__ msg, float* __restrict__ summed)
{
    __shared__ int ncnt[64];
    __shared__ int nstart[64];
    __shared__ int cur[64];
    __shared__ int pstage[BCAP];

    int t = threadIdx.x;
    int b = blockIdx.x;
    int m = gnext[b]; if (m > BCAP) m = BCAP;
    const int* pb = pairs + b * BCAP;

    if (t < 64) ncnt[t] = 0;
    __syncthreads();
    for (int i = t; i < m; i += 256) {
        atomicAdd(&ncnt[(unsigned)pb[i] >> 24], 1);
    }
    __syncthreads();

    if (t < 64) nstart[t] = ncnt[t];
    __syncthreads();
    for (int d = 1; d < 64; d <<= 1) {
        int v = 0;
        if (t < 64) { v = nstart[t]; if (t >= d) v += nstart[t - d]; }
        __syncthreads();
        if (t < 64) nstart[t] = v;
        __syncthreads();
    }
    if (t < 64) {
        int ex = nstart[t] - ncnt[t];
        nstart[t] = ex;
        cur[t] = ex;
    }
    __syncthreads();

    for (int i = t; i < m; i += 256) {
        unsigned p = (unsigned)pb[i];
        int r = atomicAdd(&cur[p >> 24], 1);
        pstage[r] = (int)(p & 0xFFFFFFu);
    }
    __syncthreads();

    {
        int nl   = t >> 2;
        int lane = t & 3;
        int d = ncnt[nl];
        int s = nstart[nl];
        float4 alo = make_float4(0.f, 0.f, 0.f, 0.f);
        float4 ahi = make_float4(0.f, 0.f, 0.f, 0.f);
        #pragma unroll 4
        for (int i = 0; i < d; ++i) {
            int e = pstage[s + i];
            uint4 v = *(const uint4*)(msg + (size_t)e * HID + lane * 8);
            float2 f0 = __half22float2(*(__half2*)&v.x);
            float2 f1 = __half22float2(*(__half2*)&v.y);
            float2 f2 = __half22float2(*(__half2*)&v.z);
            float2 f3 = __half22float2(*(__half2*)&v.w);
            alo.x += f0.x; alo.y += f0.y; alo.z += f1.x; alo.w += f1.y;
            ahi.x += f2.x; ahi.y += f2.y; ahi.z += f3.x; ahi.w += f3.y;
        }
        int node = b * 64 + nl;
        if (node < NN) {
            float inv = 1.f / fmaxf((float)d, 1.f);
            alo.x *= inv; alo.y *= inv; alo.z *= inv; alo.w *= inv;
            ahi.x *= inv; ahi.y *= inv; ahi.z *= inv; ahi.w *= inv;
            float4* op = (float4*)&summed[(size_t)node * HID];
            op[lane * 2]     = alo;
            op[lane * 2 + 1] = ahi;
        }
    }
}

// ======================= fallback path (round-5, CSR) =====================

__global__ __launch_bounds__(256) void hist_kernel(const int* __restrict__ ei,
                                                   int* __restrict__ cnt)
{
    int e = blockIdx.x * 256 + threadIdx.x;
    if (e >= NE) return;
    atomicAdd(&cnt[ei[NE + e]], 1);
}

__global__ __launch_bounds__(1024) void scanA_kernel(const int* __restrict__ cnt,
                                                     int* __restrict__ off,
                                                     int* __restrict__ bsum)
{
    __shared__ int s[1024];
    int t = threadIdx.x;
    int i = blockIdx.x * 1024 + t;
    int v = (i < NN) ? cnt[i] : 0;
    s[t] = v;
    __syncthreads();
    for (int d = 1; d < 1024; d <<= 1) {
        int a = (t >= d) ? s[t - d] : 0;
        __syncthreads();
        s[t] += a;
        __syncthreads();
    }
    if (i < NN) off[i] = s[t] - v;
    if (t == 1023) bsum[blockIdx.x] = s[1023];
}

__global__ void scanB_kernel(int* __restrict__ bsum, int* __restrict__ boff)
{
    if (threadIdx.x == 0 && blockIdx.x == 0) {
        int run = 0;
        for (int b = 0; b < NB; ++b) { boff[b] = run; run += bsum[b]; }
    }
}

__global__ __launch_bounds__(256) void scanC_kernel(int* __restrict__ off,
                                                    const int* __restrict__ boff,
                                                    int* __restrict__ next)
{
    int i = blockIdx.x * 256 + threadIdx.x;
    if (i >= NN) return;
    int o = off[i] + boff[i >> 10];
    off[i] = o;
    next[i] = o;
}

__global__ __launch_bounds__(256) void edge_mlp_scatter_kernel(
    const float* __restrict__ x, const int* __restrict__ ei,
    const float* __restrict__ ea,
    const float* __restrict__ W1, const float* __restrict__ b1,
    const float* __restrict__ W2, const float* __restrict__ b2,
    int* __restrict__ next, __half* __restrict__ msg)
{
    int e = blockIdx.x * 256 + threadIdx.x;
    if (e >= NE) return;
    int row = ei[e];
    int col = ei[NE + e];
    int pos = atomicAdd(&next[col], 1);

    float in[FN + FE];
    #pragma unroll
    for (int k = 0; k < FN; ++k) in[k] = x[row * FN + k];
    const float2* ep = (const float2*)&ea[(size_t)e * FE];
    #pragma unroll
    for (int k = 0; k < FE / 2; ++k) {
        float2 v = ep[k];
        in[FN + 2*k] = v.x; in[FN + 2*k + 1] = v.y;
    }

    float h[HID];
    #pragma unroll
    for (int j = 0; j < HID; ++j) {
        float a = b1[j];
        #pragma unroll
        for (int k = 0; k < FN + FE; ++k) a = fmaf(in[k], W1[k * HID + j], a);
        h[j] = leaky(a);
    }
    float o[HID];
    #pragma unroll
    for (int j = 0; j < HID; ++j) {
        float a = b2[j];
        #pragma unroll
        for (int k = 0; k < HID; ++k) a = fmaf(h[k], W2[k * HID + j], a);
        o[j] = a;
    }

    __half2 hh[HID / 2];
    #pragma unroll
    for (int q = 0; q < HID / 2; ++q) hh[q] = __floats2half2_rn(o[2*q], o[2*q+1]);
    uint4* dst = (uint4*)(msg + (size_t)pos * HID);
    const uint4* src = (const uint4*)hh;
    #pragma unroll
    for (int q = 0; q < 4; ++q) dst[q] = src[q];
}

__global__ __launch_bounds__(256) void mean_csr_kernel(
    const __half* __restrict__ msg, const int* __restrict__ off,
    const int* __restrict__ cnt, float* __restrict__ summed)
{
    int gid = blockIdx.x * 256 + threadIdx.x;
    int node = gid >> 3;
    int lane = gid & 7;
    if (node >= NN) return;
    int t0 = off[node], d = cnt[node];

    float4 acc = make_float4(0.f, 0.f, 0.f, 0.f);
    const __half2* p = (const __half2*)(msg + (size_t)t0 * HID + lane * 4);
    for (int t = 0; t < d; ++t) {
        __half2 a = p[0], b = p[1];
        float2 fa = __half22float2(a), fb = __half22float2(b);
        acc.x += fa.x; acc.y += fa.y; acc.z += fb.x; acc.w += fb.y;
        p += HID / 2;
    }
    float inv = 1.f / fmaxf((float)d, 1.f);
    acc.x *= inv; acc.y *= inv; acc.z *= inv; acc.w *= inv;
    ((float4*)&summed[(size_t)node * HID])[lane] = acc;
}

// ======================= node MLP (shared) ================================

__global__ __launch_bounds__(256) void node_kernel(
    const float* __restrict__ x, const float* __restrict__ summed,
    const float* __restrict__ u,
    const int* __restrict__ batch,
    const float* __restrict__ W3, const float* __restrict__ b3,
    const float* __restrict__ W4, const float* __restrict__ b4,
    float* __restrict__ out)
{
    __shared__ __align__(16) float sW3[(FN + HID + FG) * HID];
    __shared__ __align__(16) float sW4[HID * FN];
    __shared__ __align__(16) float sb3[HID];
    __shared__ float sb4[FN];
    int tid = threadIdx.x;
    for (int i = tid; i < (FN + HID + FG) * HID; i += 256) sW3[i] = W3[i];
    for (int i = tid; i < HID * FN; i += 256) sW4[i] = W4[i];
    if (tid < HID) sb3[tid] = b3[tid];
    if (tid < FN) sb4[tid] = b4[tid];
    __syncthreads();

    int i = blockIdx.x * 256 + tid;
    if (i >= NN) return;

    float g[HID];
    #pragma unroll
    for (int jq = 0; jq < HID / 4; ++jq) {
        float4 bb = ((const float4*)sb3)[jq];
        g[4*jq+0] = bb.x; g[4*jq+1] = bb.y; g[4*jq+2] = bb.z; g[4*jq+3] = bb.w;
    }

    #pragma unroll
    for (int k = 0; k < FN; ++k) {
        float a = x[i * FN + k];
        const float4* wr = (const float4*)(sW3 + k * HID);
        #pragma unroll
        for (int jq = 0; jq < HID / 4; ++jq) {
            float4 w = wr[jq];
            g[4*jq+0] = fmaf(a, w.x, g[4*jq+0]);
            g[4*jq+1] = fmaf(a, w.y, g[4*jq+1]);
            g[4*jq+2] = fmaf(a, w.z, g[4*jq+2]);
            g[4*jq+3] = fmaf(a, w.w, g[4*jq+3]);
        }
    }

    const float4* sp = (const float4*)&summed[(size_t)i * HID];
    #pragma unroll
    for (int kq = 0; kq < HID / 4; ++kq) {
        float4 mvv = sp[kq];
        #pragma unroll
        for (int c = 0; c < 4; ++c) {
            float a = (c == 0) ? mvv.x : (c == 1) ? mvv.y : (c == 2) ? mvv.z : mvv.w;
            const float4* wr = (const float4*)(sW3 + (FN + 4*kq + c) * HID);
            #pragma unroll
            for (int jq = 0; jq < HID / 4; ++jq) {
                float4 w = wr[jq];
                g[4*jq+0] = fmaf(a, w.x, g[4*jq+0]);
                g[4*jq+1] = fmaf(a, w.y, g[4*jq+1]);
                g[4*jq+2] = fmaf(a, w.z, g[4*jq+2]);
                g[4*jq+3] = fmaf(a, w.w, g[4*jq+3]);
            }
        }
    }

    int b = batch[i];
    const float4* up = (const float4*)&u[(size_t)b * FG];
    #pragma unroll
    for (int kq = 0; kq < FG / 4; ++kq) {
        float4 uvv = up[kq];
        #pragma unroll
        for (int c = 0; c < 4; ++c) {
            float a = (c == 0) ? uvv.x : (c == 1) ? uvv.y : (c == 2) ? uvv.z : uvv.w;
            const float4* wr = (const float4*)(sW3 + (FN + HID + 4*kq + c) * HID);
            #pragma unroll
            for (int jq = 0; jq < HID / 4; ++jq) {
                float4 w = wr[jq];
                g[4*jq+0] = fmaf(a, w.x, g[4*jq+0]);
                g[4*jq+1] = fmaf(a, w.y, g[4*jq+1]);
                g[4*jq+2] = fmaf(a, w.z, g[4*jq+2]);
                g[4*jq+3] = fmaf(a, w.w, g[4*jq+3]);
            }
        }
    }

    #pragma unroll
    for (int j = 0; j < HID; ++j) g[j] = leaky(g[j]);

    #pragma unroll
    for (int j = 0; j < FN; ++j) {
        float acc = sb4[j];
        #pragma unroll
        for (int k = 0; k < HID; ++k) acc = fmaf(g[k], sW4[k * FN + j], acc);
        out[i * FN + j] = acc;
    }
}

// ======================= launch ===========================================

extern "C" void kernel_launch(void* const* d_in, const int* in_sizes, int n_in,
                              void* d_out, int out_size, void* d_ws, size_t ws_size,
                              hipStream_t stream)
{
    const float* x   = (const float*)d_in[0];
    const int*   ei  = (const int*)  d_in[1];
    const float* ea  = (const float*)d_in[2];
    const float* u   = (const float*)d_in[3];
    const int*   bat = (const int*)  d_in[4];
    const float* W1  = (const float*)d_in[5];
    const float* b1  = (const float*)d_in[6];
    const float* W2  = (const float*)d_in[7];
    const float* b2  = (const float*)d_in[8];
    const float* W3  = (const float*)d_in[9];
    const float* b3  = (const float*)d_in[10];
    const float* W4  = (const float*)d_in[11];
    const float* b4  = (const float*)d_in[12];
    float* out = (float*)d_out;

    // primary layout: gnext[1600] | w1f[1024 f16] | w2f[1024 f16] |
    //                 pairs[NBKT*BCAP] | summed[NN*HID f32] | msg[NE*HID f16]
    int*      gnext  = (int*)d_ws;
    _Float16* w1f    = (_Float16*)(gnext + 1600);
    _Float16* w2f    = w1f + 1024;
    int*      pairs  = (int*)(w2f + 1024);
    float*    summed = (float*)(pairs + (size_t)NBKT * BCAP);
    __half*   msg    = (__half*)(summed + (size_t)NN * HID);
    size_t    need   = (size_t)((char*)(msg + (size_t)NE * HID) - (char*)d_ws);

    if (ws_size >= need) {
        hipMemsetAsync(gnext, 0, 1600 * sizeof(int), stream);
        wprep_kernel<<<1, 256, 0, stream>>>(W1, W2, w1f, w2f);
        p1_edge_kernel<<<NBLK1 + NEBLK, 256, 0, stream>>>(
            x, ei, ea, w1f, b1, w2f, b2, gnext, pairs, msg);
        p2_mean_kernel<<<NBKT, 256, 0, stream>>>(pairs, gnext, msg, summed);
        node_kernel<<<(NN + 255) / 256, 256, 0, stream>>>(
            x, summed, u, bat, W3, b3, W4, b4, out);
        return;
    }

    // fallback layout (round-5): cnt|off|next|bsum|boff|summed|msg
    int*    fcnt    = (int*)d_ws;
    int*    foff    = fcnt + NN;
    int*    fnext   = foff + NN;
    int*    fbsum   = fnext + NN;
    int*    fboff   = fbsum + NB;
    float*  fsummed = (float*)(fboff + NB);
    __half* fmsg    = (__half*)(fsummed + (size_t)NN * HID);

    hipMemsetAsync(fcnt, 0, (size_t)NN * sizeof(int), stream);
    hist_kernel<<<(NE + 255) / 256, 256, 0, stream>>>(ei, fcnt);
    scanA_kernel<<<NB, 1024, 0, stream>>>(fcnt, foff, fbsum);
    scanB_kernel<<<1, 64, 0, stream>>>(fbsum, fboff);
    scanC_kernel<<<(NN + 255) / 256, 256, 0, stream>>>(foff, fboff, fnext);
    edge_mlp_scatter_kernel<<<(NE + 255) / 256, 256, 0, stream>>>(
        x, ei, ea, W1, b1, W2, b2, fnext, fmsg);
    mean_csr_kernel<<<(NN * 8 + 255) / 256, 256, 0, stream>>>(fmsg, foff, fcnt, fsummed);
    node_kernel<<<(NN + 255) / 256, 256, 0, stream>>>(
        x, fsummed, u, bat, W3, b3, W4, b4, out);
}